// Round 11
// baseline (342.679 us; speedup 1.0000x reference)
//
#include <hip/hip_runtime.h>
#include <math.h>

#define NN 50000
#define NE 800000
#define SLOPE 0.2f
#define NB 49        // ceil(50000 / 1024)
#define GEMMB 782    // ceil(50000 / 64) gemm blocks per side
#define EDGEB 3125   // ceil(800000 / 256) edge-parallel blocks

typedef __attribute__((ext_vector_type(8))) short bf16x8;
typedef __attribute__((ext_vector_type(4))) float f32x4;

// split fp32 into two bf16 halves: v ~= hi + lo, residual ~2^-16 * |v|.
static __device__ __forceinline__ void split_bf16(float v, unsigned short& h,
                                                  unsigned short& l) {
  unsigned u = __float_as_uint(v);
  h = (unsigned short)(u >> 16);
  float hf = __uint_as_float(((unsigned)h) << 16);
  float r = v - hf;
  l = (unsigned short)(__float_as_uint(r) >> 16);
}

// ---------------- MFMA split-bf16 gemm body ----------------
// 64 nodes x 128 cols per block, K=128 in 4 chunks of 32. 4 waves, each owns a
// 16-row strip. C = xh@wh + xl@wh + xh@wl on the matrix pipe (r10: -37 us,
// absmax unchanged). A-frags now load DIRECTLY from global (two float4/lane;
// each 64B line covered exactly by 4 lanes) -- no x LDS staging. LDS 20.5 KB
// (was 30.7) -> 7 co-resident blocks/CU for the fused edge halves.
//   A: row=lane&15, k=8*(lane>>4)+i   B: col=lane&15, same k
//   C: col=lane&15, row=4*(lane>>4)+reg   (m89-verified, r10-proven)

__device__ __forceinline__ void gemm_body(int bx, const float* __restrict__ x,
                                          const float* __restrict__ W,
                                          const float* __restrict__ bptr,
                                          float* __restrict__ optr,
                                          unsigned short* wh_s, unsigned short* wl_s) {
  int tid = threadIdx.x;
  int w = tid >> 6;
  int l = tid & 63;
  int n0 = bx * 64;

  int arow = n0 + 16 * w + (l & 15);
  if (arow >= NN) arow = NN - 1;  // clamp: C rows >= NN never stored
  int ko = (l >> 4) * 8;
  const float* xp = x + (size_t)arow * 128 + ko;

  f32x4 acc[8];
#pragma unroll
  for (int i = 0; i < 8; ++i) acc[i] = (f32x4){0.f, 0.f, 0.f, 0.f};

  for (int kb = 0; kb < 128; kb += 32) {
    // stage W chunk transposed (col-major for B frags), stride 40
    {
      int col = tid & 127;
      int kk0 = (tid >> 7) * 16;
      unsigned short h[16], lo[16];
#pragma unroll
      for (int j = 0; j < 16; ++j)
        split_bf16(W[(size_t)(kb + kk0 + j) * 128 + col], h[j], lo[j]);
      bf16x8 hv0, hv1, lv0, lv1;
#pragma unroll
      for (int i = 0; i < 8; ++i) {
        hv0[i] = (short)h[i]; hv1[i] = (short)h[8 + i];
        lv0[i] = (short)lo[i]; lv1[i] = (short)lo[8 + i];
      }
      *(bf16x8*)&wh_s[col * 40 + kk0] = hv0;
      *(bf16x8*)&wh_s[col * 40 + kk0 + 8] = hv1;
      *(bf16x8*)&wl_s[col * 40 + kk0] = lv0;
      *(bf16x8*)&wl_s[col * 40 + kk0 + 8] = lv1;
    }
    // A frags straight from global
    float4 v0 = *(const float4*)(xp + kb);
    float4 v1 = *(const float4*)(xp + kb + 4);
    unsigned short h[8], lo[8];
    split_bf16(v0.x, h[0], lo[0]); split_bf16(v0.y, h[1], lo[1]);
    split_bf16(v0.z, h[2], lo[2]); split_bf16(v0.w, h[3], lo[3]);
    split_bf16(v1.x, h[4], lo[4]); split_bf16(v1.y, h[5], lo[5]);
    split_bf16(v1.z, h[6], lo[6]); split_bf16(v1.w, h[7], lo[7]);
    bf16x8 ah, al;
#pragma unroll
    for (int i = 0; i < 8; ++i) { ah[i] = (short)h[i]; al[i] = (short)lo[i]; }
    __syncthreads();

#pragma unroll
    for (int ct = 0; ct < 8; ++ct) {
      int cbase = (ct * 16 + (l & 15)) * 40 + ko;
      bf16x8 bh = *(bf16x8*)&wh_s[cbase];
      bf16x8 bl = *(bf16x8*)&wl_s[cbase];
      acc[ct] = __builtin_amdgcn_mfma_f32_16x16x32_bf16(ah, bh, acc[ct], 0, 0, 0);
      acc[ct] = __builtin_amdgcn_mfma_f32_16x16x32_bf16(al, bh, acc[ct], 0, 0, 0);
      acc[ct] = __builtin_amdgcn_mfma_f32_16x16x32_bf16(ah, bl, acc[ct], 0, 0, 0);
    }
    __syncthreads();
  }

  int colb = l & 15;
  int rq = (l >> 4) * 4;
#pragma unroll
  for (int ct = 0; ct < 8; ++ct) {
    float bvv = bptr[ct * 16 + colb];
#pragma unroll
    for (int r = 0; r < 4; ++r) {
      int gn = n0 + 16 * w + rq + r;
      if (gn < NN) optr[(size_t)gn * 128 + ct * 16 + colb] = acc[ct][r] + bvv;
    }
  }
}

// ---------------- fused launch A: gemm_L (MFMA) + deg ----------------

__launch_bounds__(256)
__global__ void fusedA_kernel(const float* __restrict__ x,
                              const float* __restrict__ W_l, const float* __restrict__ b_l,
                              float* __restrict__ x_l,
                              const int* __restrict__ tgt, int* __restrict__ deg) {
  __shared__ unsigned short wh_s[128 * 40], wl_s[128 * 40];
  if (blockIdx.x < GEMMB) {
    gemm_body(blockIdx.x, x, W_l, b_l, x_l, wh_s, wl_s);
  } else {
    int e = (blockIdx.x - GEMMB) * 256 + threadIdx.x;
    if (e < NE) atomicAdd(&deg[tgt[e]], 1);
  }
}

// ---------------- fused launch B: gemm_R (MFMA) + slim scatter ----------------
// Scatter payload back to 8B int2(src, eid): the 64B eattr pre-gather moved
// ~100MB through this kernel and was net-neutral for gat once the 4-wide MLP
// exists (r5/r6 accounting). gat re-reads attrs via eid with 4 independent
// s_load chains instead.

__launch_bounds__(256)
__global__ void fusedB_kernel(const float* __restrict__ x,
                              const float* __restrict__ W_r, const float* __restrict__ b_r,
                              float* __restrict__ x_r,
                              const int* __restrict__ src, const int* __restrict__ tgt,
                              int* __restrict__ cursor, int2* __restrict__ csr) {
  __shared__ unsigned short wh_s[128 * 40], wl_s[128 * 40];
  if (blockIdx.x < GEMMB) {
    gemm_body(blockIdx.x, x, W_r, b_r, x_r, wh_s, wl_s);
  } else {
    int e = (blockIdx.x - GEMMB) * 256 + threadIdx.x;
    if (e < NE) {
      int t = tgt[e];
      int pos = atomicAdd(&cursor[t], 1);
      csr[pos] = make_int2(src[e], e);
    }
  }
}

// ---------------- CSR prefix-scan (2 kernels) ----------------

__global__ void partial_kernel(const int* __restrict__ deg, int* __restrict__ psum) {
  int b = blockIdx.x;
  int base = b * 1024 + threadIdx.x * 4;
  int s = 0;
  if (base + 3 < NN) {
    int4 v = *(const int4*)(deg + base);
    s = v.x + v.y + v.z + v.w;
  } else {
#pragma unroll
    for (int i = 0; i < 4; ++i)
      if (base + i < NN) s += deg[base + i];
  }
  s += __shfl_xor(s, 1);
  s += __shfl_xor(s, 2);
  s += __shfl_xor(s, 4);
  s += __shfl_xor(s, 8);
  s += __shfl_xor(s, 16);
  s += __shfl_xor(s, 32);
  __shared__ int wsum[4];
  if ((threadIdx.x & 63) == 0) wsum[threadIdx.x >> 6] = s;
  __syncthreads();
  if (threadIdx.x == 0) psum[b] = wsum[0] + wsum[1] + wsum[2] + wsum[3];
}

// Each block redundantly wave-scans the 49 psums; writes rowptr AND cursor.
__global__ void final_kernel(const int* __restrict__ deg, const int* __restrict__ psum,
                             int* __restrict__ rowptr, int* __restrict__ cursor) {
  __shared__ int offs_s;
  __shared__ int wtot[4];
  int b = blockIdx.x;
  int t = threadIdx.x;
  if (t < 64) {
    int lane = t;
    int mine = (lane < NB) ? psum[lane] : 0;
    int v = mine;
#pragma unroll
    for (int off = 1; off < 64; off <<= 1) {
      int u = __shfl_up(v, off);
      if (lane >= off) v += u;
    }
    if (lane == b) offs_s = v - mine;
    if (b == 0 && lane == 63) rowptr[NN] = v;
  }
  __syncthreads();

  int base = b * 1024 + t * 4;
  int d0 = 0, d1 = 0, d2 = 0, d3 = 0;
  if (base + 3 < NN) {
    int4 v = *(const int4*)(deg + base);
    d0 = v.x; d1 = v.y; d2 = v.z; d3 = v.w;
  } else {
    if (base < NN) d0 = deg[base];
    if (base + 1 < NN) d1 = deg[base + 1];
    if (base + 2 < NN) d2 = deg[base + 2];
  }
  int s = d0 + d1 + d2 + d3;
  int lane = t & 63, w = t >> 6;
  int v = s;
#pragma unroll
  for (int off = 1; off < 64; off <<= 1) {
    int u = __shfl_up(v, off);
    if (lane >= off) v += u;
  }
  if (lane == 63) wtot[w] = v;
  __syncthreads();
  int woff = 0;
#pragma unroll
  for (int i = 0; i < 4; ++i)
    if (i < w) woff += wtot[i];
  int run = offs_s + woff + (v - s);
  if (base < NN)     { rowptr[base] = run;     cursor[base] = run;     run += d0; }
  if (base + 1 < NN) { rowptr[base + 1] = run; cursor[base + 1] = run; run += d1; }
  if (base + 2 < NN) { rowptr[base + 2] = run; cursor[base + 2] = run; run += d2; }
  if (base + 3 < NN) { rowptr[base + 3] = run; cursor[base + 3] = run; }
}

// ---------------- main GATv2 kernel ----------------
// 4-wide edge loop; attrs via eid (4 independent s_load_dwordx16 chains,
// MLP-covered); x_l gathers hoisted. Rest identical to r7-r10.

#define EDGE_PROC(AV, XL)                                              \
  {                                                                    \
    float e0 = AV[0] * wek[0].x;                                       \
    e0 = fmaf(AV[1], wek[1].x, e0);   e0 = fmaf(AV[2], wek[2].x, e0);  \
    e0 = fmaf(AV[3], wek[3].x, e0);   e0 = fmaf(AV[4], wek[4].x, e0);  \
    e0 = fmaf(AV[5], wek[5].x, e0);   e0 = fmaf(AV[6], wek[6].x, e0);  \
    e0 = fmaf(AV[7], wek[7].x, e0);   e0 = fmaf(AV[8], wek[8].x, e0);  \
    e0 = fmaf(AV[9], wek[9].x, e0);   e0 = fmaf(AV[10], wek[10].x, e0);\
    e0 = fmaf(AV[11], wek[11].x, e0); e0 = fmaf(AV[12], wek[12].x, e0);\
    e0 = fmaf(AV[13], wek[13].x, e0); e0 = fmaf(AV[14], wek[14].x, e0);\
    e0 = fmaf(AV[15], wek[15].x, e0);                                  \
    float e1 = AV[0] * wek[0].y;                                       \
    e1 = fmaf(AV[1], wek[1].y, e1);   e1 = fmaf(AV[2], wek[2].y, e1);  \
    e1 = fmaf(AV[3], wek[3].y, e1);   e1 = fmaf(AV[4], wek[4].y, e1);  \
    e1 = fmaf(AV[5], wek[5].y, e1);   e1 = fmaf(AV[6], wek[6].y, e1);  \
    e1 = fmaf(AV[7], wek[7].y, e1);   e1 = fmaf(AV[8], wek[8].y, e1);  \
    e1 = fmaf(AV[9], wek[9].y, e1);   e1 = fmaf(AV[10], wek[10].y, e1);\
    e1 = fmaf(AV[11], wek[11].y, e1); e1 = fmaf(AV[12], wek[12].y, e1);\
    e1 = fmaf(AV[13], wek[13].y, e1); e1 = fmaf(AV[14], wek[14].y, e1);\
    e1 = fmaf(AV[15], wek[15].y, e1);                                  \
    es0 += e0; es1 += e1;                                              \
    float m0 = (XL.x + xr.x) + e0;                                     \
    float m1 = (XL.y + xr.y) + e1;                                     \
    float lm0 = fmaf(SLOPE, fminf(m0, 0.f), fmaxf(m0, 0.f));           \
    float lm1 = fmaf(SLOPE, fminf(m1, 0.f), fmaxf(m1, 0.f));           \
    float part = fmaf(attv.y, lm1, attv.x * lm0);                      \
    part += __shfl_xor(part, 1);                                       \
    part += __shfl_xor(part, 2);                                       \
    part += __shfl_xor(part, 4);                                       \
    part += __shfl_xor(part, 8);                                       \
    float p = __expf(part);                                            \
    lh += p;                                                           \
    acc0 = fmaf(p, XL.x, acc0);                                        \
    acc1 = fmaf(p, XL.y, acc1);                                        \
  }

__launch_bounds__(256)
__global__ void gat_kernel(const float* __restrict__ x_l, const float* __restrict__ x_r,
                           const int* __restrict__ rowptr, const int2* __restrict__ csr,
                           const float* __restrict__ eattr, const float* __restrict__ W_e,
                           const float* __restrict__ att, const float* __restrict__ bias,
                           float* __restrict__ out) {
  int wid = threadIdx.x >> 6;
  int lane = threadIdx.x & 63;
  int tbase = (blockIdx.x * 4 + wid) * 4;  // 3125*4*4 == 50000

  float2 wek[16];
#pragma unroll
  for (int k = 0; k < 16; ++k)
    wek[k] = *(const float2*)(W_e + k * 128 + 2 * lane);
  float2 attv = *(const float2*)(att + 2 * lane);
  float bv = bias[(2 * lane) & 31];
  float bv1 = bias[((2 * lane) & 31) + 1];

  for (int tt = 0; tt < 4; ++tt) {
    int t = tbase + tt;
    float2 xr = *(const float2*)(x_r + (size_t)t * 128 + 2 * lane);
    int start = __builtin_amdgcn_readfirstlane(rowptr[t]);
    int end = __builtin_amdgcn_readfirstlane(rowptr[t + 1]);

    float lh = 0.f, acc0 = 0.f, acc1 = 0.f, es0 = 0.f, es1 = 0.f;

    int j = start;
    for (; j + 4 <= end; j += 4) {
      int2 ce0 = csr[j];
      int2 ce1 = csr[j + 1];
      int2 ce2 = csr[j + 2];
      int2 ce3 = csr[j + 3];
      int s0 = __builtin_amdgcn_readfirstlane(ce0.x);
      int d0i = __builtin_amdgcn_readfirstlane(ce0.y);
      int s1 = __builtin_amdgcn_readfirstlane(ce1.x);
      int d1i = __builtin_amdgcn_readfirstlane(ce1.y);
      int s2 = __builtin_amdgcn_readfirstlane(ce2.x);
      int d2i = __builtin_amdgcn_readfirstlane(ce2.y);
      int s3 = __builtin_amdgcn_readfirstlane(ce3.x);
      int d3i = __builtin_amdgcn_readfirstlane(ce3.y);
      float2 xl0 = *(const float2*)(x_l + (size_t)s0 * 128 + 2 * lane);
      float2 xl1 = *(const float2*)(x_l + (size_t)s1 * 128 + 2 * lane);
      float2 xl2 = *(const float2*)(x_l + (size_t)s2 * 128 + 2 * lane);
      float2 xl3 = *(const float2*)(x_l + (size_t)s3 * 128 + 2 * lane);
      const float* ap0 = eattr + (size_t)d0i * 16;
      const float* ap1 = eattr + (size_t)d1i * 16;
      const float* ap2 = eattr + (size_t)d2i * 16;
      const float* ap3 = eattr + (size_t)d3i * 16;
      float a0[16], a1[16], a2[16], a3[16];
#pragma unroll
      for (int k = 0; k < 16; ++k) a0[k] = ap0[k];
#pragma unroll
      for (int k = 0; k < 16; ++k) a1[k] = ap1[k];
#pragma unroll
      for (int k = 0; k < 16; ++k) a2[k] = ap2[k];
#pragma unroll
      for (int k = 0; k < 16; ++k) a3[k] = ap3[k];
      EDGE_PROC(a0, xl0)
      EDGE_PROC(a1, xl1)
      EDGE_PROC(a2, xl2)
      EDGE_PROC(a3, xl3)
    }
    if (j + 2 <= end) {
      int2 ceA = csr[j];
      int2 ceB = csr[j + 1];
      int srcA = __builtin_amdgcn_readfirstlane(ceA.x);
      int eidA = __builtin_amdgcn_readfirstlane(ceA.y);
      int srcB = __builtin_amdgcn_readfirstlane(ceB.x);
      int eidB = __builtin_amdgcn_readfirstlane(ceB.y);
      const float* apA = eattr + (size_t)eidA * 16;
      const float* apB = eattr + (size_t)eidB * 16;
      float aA[16], aB[16];
#pragma unroll
      for (int k = 0; k < 16; ++k) aA[k] = apA[k];
#pragma unroll
      for (int k = 0; k < 16; ++k) aB[k] = apB[k];
      float2 xlA = *(const float2*)(x_l + (size_t)srcA * 128 + 2 * lane);
      float2 xlB = *(const float2*)(x_l + (size_t)srcB * 128 + 2 * lane);
      EDGE_PROC(aA, xlA)
      EDGE_PROC(aB, xlB)
      j += 2;
    }
    if (j < end) {
      int2 ce = csr[j];
      int srcn = __builtin_amdgcn_readfirstlane(ce.x);
      int eid = __builtin_amdgcn_readfirstlane(ce.y);
      const float* ap = eattr + (size_t)eid * 16;
      float aC[16];
#pragma unroll
      for (int k = 0; k < 16; ++k) aC[k] = ap[k];
      float2 xlC = *(const float2*)(x_l + (size_t)srcn * 128 + 2 * lane);
      EDGE_PROC(aC, xlC)
    }

    // self-loop: e = es / max(deg,1); message source is x_l[t]
    {
      float rdeg = 1.0f / fmaxf((float)(end - start), 1.0f);
      float e0 = es0 * rdeg, e1 = es1 * rdeg;
      float2 xl = *(const float2*)(x_l + (size_t)t * 128 + 2 * lane);
      float m0 = (xl.x + xr.x) + e0;
      float m1 = (xl.y + xr.y) + e1;
      float lm0 = fmaf(SLOPE, fminf(m0, 0.f), fmaxf(m0, 0.f));
      float lm1 = fmaf(SLOPE, fminf(m1, 0.f), fmaxf(m1, 0.f));
      float part = fmaf(attv.y, lm1, attv.x * lm0);
      part += __shfl_xor(part, 1);
      part += __shfl_xor(part, 2);
      part += __shfl_xor(part, 4);
      part += __shfl_xor(part, 8);
      float p = __expf(part);
      lh += p;
      acc0 = fmaf(p, xl.x, acc0);
      acc1 = fmaf(p, xl.y, acc1);
    }

    float inv = 1.0f / lh;
    float v0 = acc0 * inv, v1 = acc1 * inv;
    v0 += __shfl_xor(v0, 16);
    v0 += __shfl_xor(v0, 32);
    v1 += __shfl_xor(v1, 16);
    v1 += __shfl_xor(v1, 32);
    if (lane < 16) {
      float o0 = fmaf(v0, 0.25f, bv);
      float o1 = fmaf(v1, 0.25f, bv1);
      o0 = fmaf(SLOPE, fminf(o0, 0.f), fmaxf(o0, 0.f));
      o1 = fmaf(SLOPE, fminf(o1, 0.f), fmaxf(o1, 0.f));
      *(float2*)(out + (size_t)t * 32 + 2 * lane) = make_float2(o0, o1);
    }
  }
}

// ---------------- launch ----------------

extern "C" void kernel_launch(void* const* d_in, const int* in_sizes, int n_in,
                              void* d_out, int out_size, void* d_ws, size_t ws_size,
                              hipStream_t stream) {
  const float* x = (const float*)d_in[0];
  const int* ei = (const int*)d_in[1];
  const float* eattr = (const float*)d_in[2];
  const float* W_l = (const float*)d_in[3];
  const float* b_l = (const float*)d_in[4];
  const float* W_r = (const float*)d_in[5];
  const float* b_r = (const float*)d_in[6];
  const float* W_e = (const float*)d_in[7];
  const float* att = (const float*)d_in[8];
  const float* bias = (const float*)d_in[9];
  float* out = (float*)d_out;

  char* ws = (char*)d_ws;
  int2* csr = (int2*)ws;                       // 6,400,000 B
  float* x_l = (float*)(ws + 6400000);         // 25,600,000 B
  float* x_r = (float*)(ws + 32000000);        // 25,600,000 B
  int* deg = (int*)(ws + 57600000);            // 200,000 B
  int* rowptr = (int*)(ws + 57800000);         // 200,004 B
  int* cursor = (int*)(ws + 58000016);         // 200,000 B
  int* psum = (int*)(ws + 58200016);           // 196 B

  hipMemsetAsync(deg, 0, NN * sizeof(int), stream);
  fusedA_kernel<<<GEMMB + EDGEB, 256, 0, stream>>>(x, W_l, b_l, x_l, ei + NE, deg);
  partial_kernel<<<NB, 256, 0, stream>>>(deg, psum);
  final_kernel<<<NB, 256, 0, stream>>>(deg, psum, rowptr, cursor);
  fusedB_kernel<<<GEMMB + EDGEB, 256, 0, stream>>>(x, W_r, b_r, x_r, ei, ei + NE, cursor, csr);
  gat_kernel<<<NN / 16, 256, 0, stream>>>(x_l, x_r, rowptr, csr, eattr, W_e, att, bias, out);
}

// Round 12
// 313.535 us; speedup vs baseline: 1.0930x; 1.0930x over previous
//
#include <hip/hip_runtime.h>
#include <math.h>

#define NN 50000
#define NE 800000
#define SLOPE 0.2f
#define NB 49        // ceil(50000 / 1024)
#define GEMMB 782    // ceil(50000 / 64) gemm blocks per side
#define EDGEB 3125   // ceil(800000 / 256) edge-parallel blocks

typedef __attribute__((ext_vector_type(8))) short bf16x8;
typedef __attribute__((ext_vector_type(4))) float f32x4;

// split fp32 into two bf16 halves: v ~= hi + lo, residual ~2^-16 * |v|.
static __device__ __forceinline__ void split_bf16(float v, unsigned short& h,
                                                  unsigned short& l) {
  unsigned u = __float_as_uint(v);
  h = (unsigned short)(u >> 16);
  float hf = __uint_as_float(((unsigned)h) << 16);
  float r = v - hf;
  l = (unsigned short)(__float_as_uint(r) >> 16);
}

// ---------------- MFMA split-bf16 gemm body (r10-proven) ----------------
// 64 nodes x 128 cols per block, K=128 in 4 chunks of 32. 4 waves, each owns a
// 16-row strip. C = xh@wh + xl@wh + xh@wl on the matrix pipe.
//   A: row=lane&15, k=8*(lane>>4)+i   B: col=lane&15, same k
//   C: col=lane&15, row=4*(lane>>4)+reg

__device__ __forceinline__ void gemm_body(int bx, const float* __restrict__ x,
                                          const float* __restrict__ W,
                                          const float* __restrict__ bptr,
                                          float* __restrict__ optr,
                                          unsigned short* xh_s, unsigned short* xl_s,
                                          unsigned short* wh_s, unsigned short* wl_s) {
  int tid = threadIdx.x;
  int w = tid >> 6;
  int l = tid & 63;
  int n0 = bx * 64;

  f32x4 acc[8];
#pragma unroll
  for (int i = 0; i < 8; ++i) acc[i] = (f32x4){0.f, 0.f, 0.f, 0.f};

  for (int kb = 0; kb < 128; kb += 32) {
    // stage x chunk (64 rows x 32 k) as split-bf16, row stride 40 (pad)
    {
      int row = tid >> 2;
      int kc = (tid & 3) * 8;
      int gn = n0 + row;
      float4 v0 = make_float4(0.f, 0.f, 0.f, 0.f);
      float4 v1 = make_float4(0.f, 0.f, 0.f, 0.f);
      if (gn < NN) {
        v0 = *(const float4*)(x + (size_t)gn * 128 + kb + kc);
        v1 = *(const float4*)(x + (size_t)gn * 128 + kb + kc + 4);
      }
      unsigned short h[8], lo[8];
      split_bf16(v0.x, h[0], lo[0]); split_bf16(v0.y, h[1], lo[1]);
      split_bf16(v0.z, h[2], lo[2]); split_bf16(v0.w, h[3], lo[3]);
      split_bf16(v1.x, h[4], lo[4]); split_bf16(v1.y, h[5], lo[5]);
      split_bf16(v1.z, h[6], lo[6]); split_bf16(v1.w, h[7], lo[7]);
      bf16x8 hv, lv;
#pragma unroll
      for (int i = 0; i < 8; ++i) { hv[i] = (short)h[i]; lv[i] = (short)lo[i]; }
      *(bf16x8*)&xh_s[row * 40 + kc] = hv;
      *(bf16x8*)&xl_s[row * 40 + kc] = lv;
    }
    // stage W chunk TRANSPOSED (col-major for B frags), stride 40
    {
      int col = tid & 127;
      int kk0 = (tid >> 7) * 16;
      unsigned short h[16], lo[16];
#pragma unroll
      for (int j = 0; j < 16; ++j)
        split_bf16(W[(size_t)(kb + kk0 + j) * 128 + col], h[j], lo[j]);
      bf16x8 hv0, hv1, lv0, lv1;
#pragma unroll
      for (int i = 0; i < 8; ++i) {
        hv0[i] = (short)h[i]; hv1[i] = (short)h[8 + i];
        lv0[i] = (short)lo[i]; lv1[i] = (short)lo[8 + i];
      }
      *(bf16x8*)&wh_s[col * 40 + kk0] = hv0;
      *(bf16x8*)&wh_s[col * 40 + kk0 + 8] = hv1;
      *(bf16x8*)&wl_s[col * 40 + kk0] = lv0;
      *(bf16x8*)&wl_s[col * 40 + kk0 + 8] = lv1;
    }
    __syncthreads();

    int r16 = 16 * w + (l & 15);
    int ko = (l >> 4) * 8;
    bf16x8 ah = *(bf16x8*)&xh_s[r16 * 40 + ko];
    bf16x8 al = *(bf16x8*)&xl_s[r16 * 40 + ko];
#pragma unroll
    for (int ct = 0; ct < 8; ++ct) {
      int cbase = (ct * 16 + (l & 15)) * 40 + ko;
      bf16x8 bh = *(bf16x8*)&wh_s[cbase];
      bf16x8 bl = *(bf16x8*)&wl_s[cbase];
      acc[ct] = __builtin_amdgcn_mfma_f32_16x16x32_bf16(ah, bh, acc[ct], 0, 0, 0);
      acc[ct] = __builtin_amdgcn_mfma_f32_16x16x32_bf16(al, bh, acc[ct], 0, 0, 0);
      acc[ct] = __builtin_amdgcn_mfma_f32_16x16x32_bf16(ah, bl, acc[ct], 0, 0, 0);
    }
    __syncthreads();
  }

  // epilogue: lane covers col=l&15, rows 4*(l>>4)+r within the wave's strip
  int colb = l & 15;
  int rq = (l >> 4) * 4;
#pragma unroll
  for (int ct = 0; ct < 8; ++ct) {
    float bvv = bptr[ct * 16 + colb];
#pragma unroll
    for (int r = 0; r < 4; ++r) {
      int gn = n0 + 16 * w + rq + r;
      if (gn < NN) optr[(size_t)gn * 128 + ct * 16 + colb] = acc[ct][r] + bvv;
    }
  }
}

// ---------------- fused launch A: gemm_L (MFMA) + deg/rank ----------------

__launch_bounds__(256)
__global__ void fusedA_kernel(const float* __restrict__ x,
                              const float* __restrict__ W_l, const float* __restrict__ b_l,
                              float* __restrict__ x_l,
                              const int* __restrict__ tgt, int* __restrict__ deg,
                              int* __restrict__ rank) {
  __shared__ unsigned short xh_s[64 * 40], xl_s[64 * 40];
  __shared__ unsigned short wh_s[128 * 40], wl_s[128 * 40];
  if (blockIdx.x < GEMMB) {
    gemm_body(blockIdx.x, x, W_l, b_l, x_l, xh_s, xl_s, wh_s, wl_s);
  } else {
    int e = (blockIdx.x - GEMMB) * 256 + threadIdx.x;
    if (e < NE) rank[e] = atomicAdd(&deg[tgt[e]], 1);
  }
}

// ---------------- fused launch B: gemm_R (MFMA) + atomic-free scatter ----------------

__launch_bounds__(256)
__global__ void fusedB_kernel(const float* __restrict__ x,
                              const float* __restrict__ W_r, const float* __restrict__ b_r,
                              float* __restrict__ x_r,
                              const int* __restrict__ src, const int* __restrict__ tgt,
                              const int* __restrict__ rank,
                              const int* __restrict__ rowptr,
                              const float4* __restrict__ eattr4,
                              int* __restrict__ csr_src,
                              float4* __restrict__ eattr_csr4) {
  __shared__ unsigned short xh_s[64 * 40], xl_s[64 * 40];
  __shared__ unsigned short wh_s[128 * 40], wl_s[128 * 40];
  if (blockIdx.x < GEMMB) {
    gemm_body(blockIdx.x, x, W_r, b_r, x_r, xh_s, xl_s, wh_s, wl_s);
  } else {
    int e = (blockIdx.x - GEMMB) * 256 + threadIdx.x;
    if (e < NE) {
      int t = tgt[e];
      int r = rank[e];
      float4 a0 = eattr4[(size_t)e * 4 + 0];
      float4 a1 = eattr4[(size_t)e * 4 + 1];
      float4 a2 = eattr4[(size_t)e * 4 + 2];
      float4 a3 = eattr4[(size_t)e * 4 + 3];
      int pos = rowptr[t] + r;
      csr_src[pos] = src[e];
      eattr_csr4[(size_t)pos * 4 + 0] = a0;
      eattr_csr4[(size_t)pos * 4 + 1] = a1;
      eattr_csr4[(size_t)pos * 4 + 2] = a2;
      eattr_csr4[(size_t)pos * 4 + 3] = a3;
    }
  }
}

// ---------------- CSR prefix-scan (2 kernels) ----------------

__global__ void partial_kernel(const int* __restrict__ deg, int* __restrict__ psum) {
  int b = blockIdx.x;
  int base = b * 1024 + threadIdx.x * 4;
  int s = 0;
  if (base + 3 < NN) {
    int4 v = *(const int4*)(deg + base);
    s = v.x + v.y + v.z + v.w;
  } else {
#pragma unroll
    for (int i = 0; i < 4; ++i)
      if (base + i < NN) s += deg[base + i];
  }
  s += __shfl_xor(s, 1);
  s += __shfl_xor(s, 2);
  s += __shfl_xor(s, 4);
  s += __shfl_xor(s, 8);
  s += __shfl_xor(s, 16);
  s += __shfl_xor(s, 32);
  __shared__ int wsum[4];
  if ((threadIdx.x & 63) == 0) wsum[threadIdx.x >> 6] = s;
  __syncthreads();
  if (threadIdx.x == 0) psum[b] = wsum[0] + wsum[1] + wsum[2] + wsum[3];
}

// Each block redundantly wave-scans the 49 psums -> no separate scanpart launch.
__global__ void final_kernel(const int* __restrict__ deg, const int* __restrict__ psum,
                             int* __restrict__ rowptr) {
  __shared__ int offs_s;
  __shared__ int wtot[4];
  int b = blockIdx.x;
  int t = threadIdx.x;
  if (t < 64) {
    int lane = t;
    int mine = (lane < NB) ? psum[lane] : 0;
    int v = mine;
#pragma unroll
    for (int off = 1; off < 64; off <<= 1) {
      int u = __shfl_up(v, off);
      if (lane >= off) v += u;
    }
    if (lane == b) offs_s = v - mine;          // this block's exclusive offset
    if (b == 0 && lane == 63) rowptr[NN] = v;  // grand total
  }
  __syncthreads();

  int base = b * 1024 + t * 4;
  int d0 = 0, d1 = 0, d2 = 0, d3 = 0;
  if (base + 3 < NN) {
    int4 v = *(const int4*)(deg + base);
    d0 = v.x; d1 = v.y; d2 = v.z; d3 = v.w;
  } else {
    if (base < NN) d0 = deg[base];
    if (base + 1 < NN) d1 = deg[base + 1];
    if (base + 2 < NN) d2 = deg[base + 2];
  }
  int s = d0 + d1 + d2 + d3;
  int lane = t & 63, w = t >> 6;
  int v = s;
#pragma unroll
  for (int off = 1; off < 64; off <<= 1) {
    int u = __shfl_up(v, off);
    if (lane >= off) v += u;
  }
  if (lane == 63) wtot[w] = v;
  __syncthreads();
  int woff = 0;
#pragma unroll
  for (int i = 0; i < 4; ++i)
    if (i < w) woff += wtot[i];
  int run = offs_s + woff + (v - s);
  if (base < NN)     { rowptr[base] = run;     run += d0; }
  if (base + 1 < NN) { rowptr[base + 1] = run; run += d1; }
  if (base + 2 < NN) { rowptr[base + 2] = run; run += d2; }
  if (base + 3 < NN) { rowptr[base + 3] = run; }
}

// ---------------- main GATv2 kernel ----------------
// One wave per 4 consecutive targets; lane L holds channels (2L, 2L+1).
// Attrs pre-gathered into CSR order (induction-based s_loads). NEW: depth-2
// software pipeline over 4-edge groups -- group g+1's csr entries and x_l rows
// load while group g computes, hiding the L2/L3 gather round-trip that the
// within-group 4-wide MLP alone couldn't (gat stuck at 101 us, VALUBusy 60%).

#define EDGE_PROC(AV, XL)                                              \
  {                                                                    \
    float e0 = AV[0] * wek[0].x;                                       \
    e0 = fmaf(AV[1], wek[1].x, e0);   e0 = fmaf(AV[2], wek[2].x, e0);  \
    e0 = fmaf(AV[3], wek[3].x, e0);   e0 = fmaf(AV[4], wek[4].x, e0);  \
    e0 = fmaf(AV[5], wek[5].x, e0);   e0 = fmaf(AV[6], wek[6].x, e0);  \
    e0 = fmaf(AV[7], wek[7].x, e0);   e0 = fmaf(AV[8], wek[8].x, e0);  \
    e0 = fmaf(AV[9], wek[9].x, e0);   e0 = fmaf(AV[10], wek[10].x, e0);\
    e0 = fmaf(AV[11], wek[11].x, e0); e0 = fmaf(AV[12], wek[12].x, e0);\
    e0 = fmaf(AV[13], wek[13].x, e0); e0 = fmaf(AV[14], wek[14].x, e0);\
    e0 = fmaf(AV[15], wek[15].x, e0);                                  \
    float e1 = AV[0] * wek[0].y;                                       \
    e1 = fmaf(AV[1], wek[1].y, e1);   e1 = fmaf(AV[2], wek[2].y, e1);  \
    e1 = fmaf(AV[3], wek[3].y, e1);   e1 = fmaf(AV[4], wek[4].y, e1);  \
    e1 = fmaf(AV[5], wek[5].y, e1);   e1 = fmaf(AV[6], wek[6].y, e1);  \
    e1 = fmaf(AV[7], wek[7].y, e1);   e1 = fmaf(AV[8], wek[8].y, e1);  \
    e1 = fmaf(AV[9], wek[9].y, e1);   e1 = fmaf(AV[10], wek[10].y, e1);\
    e1 = fmaf(AV[11], wek[11].y, e1); e1 = fmaf(AV[12], wek[12].y, e1);\
    e1 = fmaf(AV[13], wek[13].y, e1); e1 = fmaf(AV[14], wek[14].y, e1);\
    e1 = fmaf(AV[15], wek[15].y, e1);                                  \
    es0 += e0; es1 += e1;                                              \
    float m0 = (XL.x + xr.x) + e0;                                     \
    float m1 = (XL.y + xr.y) + e1;                                     \
    float lm0 = fmaf(SLOPE, fminf(m0, 0.f), fmaxf(m0, 0.f));           \
    float lm1 = fmaf(SLOPE, fminf(m1, 0.f), fmaxf(m1, 0.f));           \
    float part = fmaf(attv.y, lm1, attv.x * lm0);                      \
    part += __shfl_xor(part, 1);                                       \
    part += __shfl_xor(part, 2);                                       \
    part += __shfl_xor(part, 4);                                       \
    part += __shfl_xor(part, 8);                                       \
    float p = __expf(part);                                            \
    lh += p;                                                           \
    acc0 = fmaf(p, XL.x, acc0);                                        \
    acc1 = fmaf(p, XL.y, acc1);                                        \
  }

#define PROC_GROUP(JJ, X0, X1, X2, X3)                                 \
  {                                                                    \
    const float* ap_ = eattr_csr + (size_t)(JJ) * 16;                  \
    {                                                                  \
      float a_[16];                                                    \
      _Pragma("unroll") for (int k = 0; k < 16; ++k) a_[k] = ap_[k];   \
      EDGE_PROC(a_, X0)                                                \
    }                                                                  \
    {                                                                  \
      float a_[16];                                                    \
      _Pragma("unroll") for (int k = 0; k < 16; ++k) a_[k] = ap_[16 + k];\
      EDGE_PROC(a_, X1)                                                \
    }                                                                  \
    {                                                                  \
      float a_[16];                                                    \
      _Pragma("unroll") for (int k = 0; k < 16; ++k) a_[k] = ap_[32 + k];\
      EDGE_PROC(a_, X2)                                                \
    }                                                                  \
    {                                                                  \
      float a_[16];                                                    \
      _Pragma("unroll") for (int k = 0; k < 16; ++k) a_[k] = ap_[48 + k];\
      EDGE_PROC(a_, X3)                                                \
    }                                                                  \
  }

__launch_bounds__(256)
__global__ void gat_kernel(const float* __restrict__ x_l, const float* __restrict__ x_r,
                           const int* __restrict__ rowptr, const int* __restrict__ csr_src,
                           const float* __restrict__ eattr_csr, const float* __restrict__ W_e,
                           const float* __restrict__ att, const float* __restrict__ bias,
                           float* __restrict__ out) {
  int wid = threadIdx.x >> 6;
  int lane = threadIdx.x & 63;
  int tbase = (blockIdx.x * 4 + wid) * 4;  // 3125*4*4 == 50000

  float2 wek[16];
#pragma unroll
  for (int k = 0; k < 16; ++k)
    wek[k] = *(const float2*)(W_e + k * 128 + 2 * lane);
  float2 attv = *(const float2*)(att + 2 * lane);
  float bv = bias[(2 * lane) & 31];
  float bv1 = bias[((2 * lane) & 31) + 1];

  for (int tt = 0; tt < 4; ++tt) {
    int t = tbase + tt;
    float2 xr = *(const float2*)(x_r + (size_t)t * 128 + 2 * lane);
    int start = __builtin_amdgcn_readfirstlane(rowptr[t]);
    int end = __builtin_amdgcn_readfirstlane(rowptr[t + 1]);

    float lh = 0.f, acc0 = 0.f, acc1 = 0.f, es0 = 0.f, es1 = 0.f;

    int j = start;
    int jend = start + ((end - start) & ~3);  // full 4-edge groups

    if (j < jend) {
      // prologue: load group 0
      int s0 = __builtin_amdgcn_readfirstlane(csr_src[j]);
      int s1 = __builtin_amdgcn_readfirstlane(csr_src[j + 1]);
      int s2 = __builtin_amdgcn_readfirstlane(csr_src[j + 2]);
      int s3 = __builtin_amdgcn_readfirstlane(csr_src[j + 3]);
      float2 xc0 = *(const float2*)(x_l + (size_t)s0 * 128 + 2 * lane);
      float2 xc1 = *(const float2*)(x_l + (size_t)s1 * 128 + 2 * lane);
      float2 xc2 = *(const float2*)(x_l + (size_t)s2 * 128 + 2 * lane);
      float2 xc3 = *(const float2*)(x_l + (size_t)s3 * 128 + 2 * lane);
      // steady state: issue next group's loads, then compute current
      for (; j + 4 < jend; j += 4) {
        int n0 = __builtin_amdgcn_readfirstlane(csr_src[j + 4]);
        int n1 = __builtin_amdgcn_readfirstlane(csr_src[j + 5]);
        int n2 = __builtin_amdgcn_readfirstlane(csr_src[j + 6]);
        int n3 = __builtin_amdgcn_readfirstlane(csr_src[j + 7]);
        float2 xn0 = *(const float2*)(x_l + (size_t)n0 * 128 + 2 * lane);
        float2 xn1 = *(const float2*)(x_l + (size_t)n1 * 128 + 2 * lane);
        float2 xn2 = *(const float2*)(x_l + (size_t)n2 * 128 + 2 * lane);
        float2 xn3 = *(const float2*)(x_l + (size_t)n3 * 128 + 2 * lane);
        PROC_GROUP(j, xc0, xc1, xc2, xc3)
        xc0 = xn0; xc1 = xn1; xc2 = xn2; xc3 = xn3;
      }
      // epilogue: last full group
      PROC_GROUP(j, xc0, xc1, xc2, xc3)
      j += 4;
    }
    // tail: 0-3 edges
    for (; j < end; ++j) {
      int srcn = __builtin_amdgcn_readfirstlane(csr_src[j]);
      const float* ap = eattr_csr + (size_t)j * 16;
      float aC[16];
#pragma unroll
      for (int k = 0; k < 16; ++k) aC[k] = ap[k];
      float2 xlC = *(const float2*)(x_l + (size_t)srcn * 128 + 2 * lane);
      EDGE_PROC(aC, xlC)
    }

    // self-loop: e = es / max(deg,1); message source is x_l[t]
    {
      float rdeg = 1.0f / fmaxf((float)(end - start), 1.0f);
      float e0 = es0 * rdeg, e1 = es1 * rdeg;
      float2 xl = *(const float2*)(x_l + (size_t)t * 128 + 2 * lane);
      float m0 = (xl.x + xr.x) + e0;
      float m1 = (xl.y + xr.y) + e1;
      float lm0 = fmaf(SLOPE, fminf(m0, 0.f), fmaxf(m0, 0.f));
      float lm1 = fmaf(SLOPE, fminf(m1, 0.f), fmaxf(m1, 0.f));
      float part = fmaf(attv.y, lm1, attv.x * lm0);
      part += __shfl_xor(part, 1);
      part += __shfl_xor(part, 2);
      part += __shfl_xor(part, 4);
      part += __shfl_xor(part, 8);
      float p = __expf(part);
      lh += p;
      acc0 = fmaf(p, xl.x, acc0);
      acc1 = fmaf(p, xl.y, acc1);
    }

    float inv = 1.0f / lh;
    float v0 = acc0 * inv, v1 = acc1 * inv;
    v0 += __shfl_xor(v0, 16);
    v0 += __shfl_xor(v0, 32);
    v1 += __shfl_xor(v1, 16);
    v1 += __shfl_xor(v1, 32);
    if (lane < 16) {
      float o0 = fmaf(v0, 0.25f, bv);
      float o1 = fmaf(v1, 0.25f, bv1);
      o0 = fmaf(SLOPE, fminf(o0, 0.f), fmaxf(o0, 0.f));
      o1 = fmaf(SLOPE, fminf(o1, 0.f), fmaxf(o1, 0.f));
      *(float2*)(out + (size_t)t * 32 + 2 * lane) = make_float2(o0, o1);
    }
  }
}

// ---------------- launch ----------------

extern "C" void kernel_launch(void* const* d_in, const int* in_sizes, int n_in,
                              void* d_out, int out_size, void* d_ws, size_t ws_size,
                              hipStream_t stream) {
  const float* x = (const float*)d_in[0];
  const int* ei = (const int*)d_in[1];
  const float* eattr = (const float*)d_in[2];
  const float* W_l = (const float*)d_in[3];
  const float* b_l = (const float*)d_in[4];
  const float* W_r = (const float*)d_in[5];
  const float* b_r = (const float*)d_in[6];
  const float* W_e = (const float*)d_in[7];
  const float* att = (const float*)d_in[8];
  const float* bias = (const float*)d_in[9];
  float* out = (float*)d_out;

  char* ws = (char*)d_ws;
  int* csr_src = (int*)ws;                       // 3,200,000 B
  float* eattr_csr = (float*)(ws + 3200000);     // 51,200,000 B
  float* x_l = (float*)(ws + 54400000);          // 25,600,000 B
  float* x_r = (float*)(ws + 80000000);          // 25,600,000 B
  int* deg = (int*)(ws + 105600000);             // 200,000 B
  int* rowptr = (int*)(ws + 105800000);          // 200,004 B
  int* rank = (int*)(ws + 106000016);            // 3,200,000 B
  int* psum = (int*)(ws + 109200016);            // 196 B

  hipMemsetAsync(deg, 0, NN * sizeof(int), stream);
  fusedA_kernel<<<GEMMB + EDGEB, 256, 0, stream>>>(x, W_l, b_l, x_l, ei + NE, deg, rank);
  partial_kernel<<<NB, 256, 0, stream>>>(deg, psum);
  final_kernel<<<NB, 256, 0, stream>>>(deg, psum, rowptr);
  fusedB_kernel<<<GEMMB + EDGEB, 256, 0, stream>>>(
      x, W_r, b_r, x_r, ei, ei + NE, rank, rowptr, (const float4*)eattr,
      csr_src, (float4*)eattr_csr);
  gat_kernel<<<NN / 16, 256, 0, stream>>>(x_l, x_r, rowptr, csr_src, eattr_csr, W_e, att, bias, out);
}

// Round 13
// 300.984 us; speedup vs baseline: 1.1385x; 1.0417x over previous
//
#include <hip/hip_runtime.h>
#include <hip/hip_fp16.h>
#include <math.h>

#define NN 50000
#define NE 800000
#define SLOPE 0.2f
#define NB 49        // ceil(50000 / 1024)
#define GEMMB 782    // ceil(50000 / 64) gemm blocks per side
#define EDGEB 3125   // ceil(800000 / 256) edge-parallel blocks

typedef __attribute__((ext_vector_type(8))) short bf16x8;
typedef __attribute__((ext_vector_type(4))) float f32x4;

// split fp32 into two bf16 halves: v ~= hi + lo, residual ~2^-16 * |v|.
static __device__ __forceinline__ void split_bf16(float v, unsigned short& h,
                                                  unsigned short& l) {
  unsigned u = __float_as_uint(v);
  h = (unsigned short)(u >> 16);
  float hf = __uint_as_float(((unsigned)h) << 16);
  float r = v - hf;
  l = (unsigned short)(__float_as_uint(r) >> 16);
}

// ---------------- MFMA split-bf16 gemm body (r10-proven) ----------------
// 64 nodes x 128 cols per block, K=128 in 4 chunks of 32. 4 waves, each owns a
// 16-row strip. C = xh@wh + xl@wh + xh@wl on the matrix pipe. Output is
// stored as FP16 (halves the gat gather traffic; rel err 2^-11 << tolerance).
//   A: row=lane&15, k=8*(lane>>4)+i   B: col=lane&15, same k
//   C: col=lane&15, row=4*(lane>>4)+reg

__device__ __forceinline__ void gemm_body(int bx, const float* __restrict__ x,
                                          const float* __restrict__ W,
                                          const float* __restrict__ bptr,
                                          __half* __restrict__ optr,
                                          unsigned short* xh_s, unsigned short* xl_s,
                                          unsigned short* wh_s, unsigned short* wl_s) {
  int tid = threadIdx.x;
  int w = tid >> 6;
  int l = tid & 63;
  int n0 = bx * 64;

  f32x4 acc[8];
#pragma unroll
  for (int i = 0; i < 8; ++i) acc[i] = (f32x4){0.f, 0.f, 0.f, 0.f};

  for (int kb = 0; kb < 128; kb += 32) {
    // stage x chunk (64 rows x 32 k) as split-bf16, row stride 40 (pad)
    {
      int row = tid >> 2;
      int kc = (tid & 3) * 8;
      int gn = n0 + row;
      float4 v0 = make_float4(0.f, 0.f, 0.f, 0.f);
      float4 v1 = make_float4(0.f, 0.f, 0.f, 0.f);
      if (gn < NN) {
        v0 = *(const float4*)(x + (size_t)gn * 128 + kb + kc);
        v1 = *(const float4*)(x + (size_t)gn * 128 + kb + kc + 4);
      }
      unsigned short h[8], lo[8];
      split_bf16(v0.x, h[0], lo[0]); split_bf16(v0.y, h[1], lo[1]);
      split_bf16(v0.z, h[2], lo[2]); split_bf16(v0.w, h[3], lo[3]);
      split_bf16(v1.x, h[4], lo[4]); split_bf16(v1.y, h[5], lo[5]);
      split_bf16(v1.z, h[6], lo[6]); split_bf16(v1.w, h[7], lo[7]);
      bf16x8 hv, lv;
#pragma unroll
      for (int i = 0; i < 8; ++i) { hv[i] = (short)h[i]; lv[i] = (short)lo[i]; }
      *(bf16x8*)&xh_s[row * 40 + kc] = hv;
      *(bf16x8*)&xl_s[row * 40 + kc] = lv;
    }
    // stage W chunk TRANSPOSED (col-major for B frags), stride 40
    {
      int col = tid & 127;
      int kk0 = (tid >> 7) * 16;
      unsigned short h[16], lo[16];
#pragma unroll
      for (int j = 0; j < 16; ++j)
        split_bf16(W[(size_t)(kb + kk0 + j) * 128 + col], h[j], lo[j]);
      bf16x8 hv0, hv1, lv0, lv1;
#pragma unroll
      for (int i = 0; i < 8; ++i) {
        hv0[i] = (short)h[i]; hv1[i] = (short)h[8 + i];
        lv0[i] = (short)lo[i]; lv1[i] = (short)lo[8 + i];
      }
      *(bf16x8*)&wh_s[col * 40 + kk0] = hv0;
      *(bf16x8*)&wh_s[col * 40 + kk0 + 8] = hv1;
      *(bf16x8*)&wl_s[col * 40 + kk0] = lv0;
      *(bf16x8*)&wl_s[col * 40 + kk0 + 8] = lv1;
    }
    __syncthreads();

    int r16 = 16 * w + (l & 15);
    int ko = (l >> 4) * 8;
    bf16x8 ah = *(bf16x8*)&xh_s[r16 * 40 + ko];
    bf16x8 al = *(bf16x8*)&xl_s[r16 * 40 + ko];
#pragma unroll
    for (int ct = 0; ct < 8; ++ct) {
      int cbase = (ct * 16 + (l & 15)) * 40 + ko;
      bf16x8 bh = *(bf16x8*)&wh_s[cbase];
      bf16x8 bl = *(bf16x8*)&wl_s[cbase];
      acc[ct] = __builtin_amdgcn_mfma_f32_16x16x32_bf16(ah, bh, acc[ct], 0, 0, 0);
      acc[ct] = __builtin_amdgcn_mfma_f32_16x16x32_bf16(al, bh, acc[ct], 0, 0, 0);
      acc[ct] = __builtin_amdgcn_mfma_f32_16x16x32_bf16(ah, bl, acc[ct], 0, 0, 0);
    }
    __syncthreads();
  }

  // epilogue: lane covers col=l&15, rows 4*(l>>4)+r; store fp16
  int colb = l & 15;
  int rq = (l >> 4) * 4;
#pragma unroll
  for (int ct = 0; ct < 8; ++ct) {
    float bvv = bptr[ct * 16 + colb];
#pragma unroll
    for (int r = 0; r < 4; ++r) {
      int gn = n0 + 16 * w + rq + r;
      if (gn < NN)
        optr[(size_t)gn * 128 + ct * 16 + colb] = __float2half(acc[ct][r] + bvv);
    }
  }
}

// ---------------- fused launch A: gemm_L (MFMA) + deg/rank ----------------

__launch_bounds__(256)
__global__ void fusedA_kernel(const float* __restrict__ x,
                              const float* __restrict__ W_l, const float* __restrict__ b_l,
                              __half* __restrict__ x_l,
                              const int* __restrict__ tgt, int* __restrict__ deg,
                              int* __restrict__ rank) {
  __shared__ unsigned short xh_s[64 * 40], xl_s[64 * 40];
  __shared__ unsigned short wh_s[128 * 40], wl_s[128 * 40];
  if (blockIdx.x < GEMMB) {
    gemm_body(blockIdx.x, x, W_l, b_l, x_l, xh_s, xl_s, wh_s, wl_s);
  } else {
    int e = (blockIdx.x - GEMMB) * 256 + threadIdx.x;
    if (e < NE) rank[e] = atomicAdd(&deg[tgt[e]], 1);
  }
}

// ---------------- fused launch B: gemm_R (MFMA) + atomic-free scatter ----------------

__launch_bounds__(256)
__global__ void fusedB_kernel(const float* __restrict__ x,
                              const float* __restrict__ W_r, const float* __restrict__ b_r,
                              __half* __restrict__ x_r,
                              const int* __restrict__ src, const int* __restrict__ tgt,
                              const int* __restrict__ rank,
                              const int* __restrict__ rowptr,
                              const float4* __restrict__ eattr4,
                              int* __restrict__ csr_src,
                              float4* __restrict__ eattr_csr4) {
  __shared__ unsigned short xh_s[64 * 40], xl_s[64 * 40];
  __shared__ unsigned short wh_s[128 * 40], wl_s[128 * 40];
  if (blockIdx.x < GEMMB) {
    gemm_body(blockIdx.x, x, W_r, b_r, x_r, xh_s, xl_s, wh_s, wl_s);
  } else {
    int e = (blockIdx.x - GEMMB) * 256 + threadIdx.x;
    if (e < NE) {
      int t = tgt[e];
      int r = rank[e];
      float4 a0 = eattr4[(size_t)e * 4 + 0];
      float4 a1 = eattr4[(size_t)e * 4 + 1];
      float4 a2 = eattr4[(size_t)e * 4 + 2];
      float4 a3 = eattr4[(size_t)e * 4 + 3];
      int pos = rowptr[t] + r;
      csr_src[pos] = src[e];
      eattr_csr4[(size_t)pos * 4 + 0] = a0;
      eattr_csr4[(size_t)pos * 4 + 1] = a1;
      eattr_csr4[(size_t)pos * 4 + 2] = a2;
      eattr_csr4[(size_t)pos * 4 + 3] = a3;
    }
  }
}

// ---------------- CSR prefix-scan (2 kernels) ----------------

__global__ void partial_kernel(const int* __restrict__ deg, int* __restrict__ psum) {
  int b = blockIdx.x;
  int base = b * 1024 + threadIdx.x * 4;
  int s = 0;
  if (base + 3 < NN) {
    int4 v = *(const int4*)(deg + base);
    s = v.x + v.y + v.z + v.w;
  } else {
#pragma unroll
    for (int i = 0; i < 4; ++i)
      if (base + i < NN) s += deg[base + i];
  }
  s += __shfl_xor(s, 1);
  s += __shfl_xor(s, 2);
  s += __shfl_xor(s, 4);
  s += __shfl_xor(s, 8);
  s += __shfl_xor(s, 16);
  s += __shfl_xor(s, 32);
  __shared__ int wsum[4];
  if ((threadIdx.x & 63) == 0) wsum[threadIdx.x >> 6] = s;
  __syncthreads();
  if (threadIdx.x == 0) psum[b] = wsum[0] + wsum[1] + wsum[2] + wsum[3];
}

// Each block redundantly wave-scans the 49 psums -> no separate scanpart launch.
__global__ void final_kernel(const int* __restrict__ deg, const int* __restrict__ psum,
                             int* __restrict__ rowptr) {
  __shared__ int offs_s;
  __shared__ int wtot[4];
  int b = blockIdx.x;
  int t = threadIdx.x;
  if (t < 64) {
    int lane = t;
    int mine = (lane < NB) ? psum[lane] : 0;
    int v = mine;
#pragma unroll
    for (int off = 1; off < 64; off <<= 1) {
      int u = __shfl_up(v, off);
      if (lane >= off) v += u;
    }
    if (lane == b) offs_s = v - mine;          // this block's exclusive offset
    if (b == 0 && lane == 63) rowptr[NN] = v;  // grand total
  }
  __syncthreads();

  int base = b * 1024 + t * 4;
  int d0 = 0, d1 = 0, d2 = 0, d3 = 0;
  if (base + 3 < NN) {
    int4 v = *(const int4*)(deg + base);
    d0 = v.x; d1 = v.y; d2 = v.z; d3 = v.w;
  } else {
    if (base < NN) d0 = deg[base];
    if (base + 1 < NN) d1 = deg[base + 1];
    if (base + 2 < NN) d2 = deg[base + 2];
  }
  int s = d0 + d1 + d2 + d3;
  int lane = t & 63, w = t >> 6;
  int v = s;
#pragma unroll
  for (int off = 1; off < 64; off <<= 1) {
    int u = __shfl_up(v, off);
    if (lane >= off) v += u;
  }
  if (lane == 63) wtot[w] = v;
  __syncthreads();
  int woff = 0;
#pragma unroll
  for (int i = 0; i < 4; ++i)
    if (i < w) woff += wtot[i];
  int run = offs_s + woff + (v - s);
  if (base < NN)     { rowptr[base] = run;     run += d0; }
  if (base + 1 < NN) { rowptr[base + 1] = run; run += d1; }
  if (base + 2 < NN) { rowptr[base + 2] = run; run += d2; }
  if (base + 3 < NN) { rowptr[base + 3] = run; }
}

// ---------------- main GATv2 kernel (r10 loop; x_l/x_r now fp16) ----------------
// One wave per 4 consecutive targets; lane L holds channels (2L, 2L+1).
// Attrs pre-gathered into CSR order (induction-based s_loads); 4-wide x_l
// gather MLP. fp16 x_l halves the dominant random fetch (~175 -> ~88 MB).
// (r12's depth-2 pipeline measured neutral-negative -> reverted.)

#define EDGE_PROC(AV, XL)                                              \
  {                                                                    \
    float e0 = AV[0] * wek[0].x;                                       \
    e0 = fmaf(AV[1], wek[1].x, e0);   e0 = fmaf(AV[2], wek[2].x, e0);  \
    e0 = fmaf(AV[3], wek[3].x, e0);   e0 = fmaf(AV[4], wek[4].x, e0);  \
    e0 = fmaf(AV[5], wek[5].x, e0);   e0 = fmaf(AV[6], wek[6].x, e0);  \
    e0 = fmaf(AV[7], wek[7].x, e0);   e0 = fmaf(AV[8], wek[8].x, e0);  \
    e0 = fmaf(AV[9], wek[9].x, e0);   e0 = fmaf(AV[10], wek[10].x, e0);\
    e0 = fmaf(AV[11], wek[11].x, e0); e0 = fmaf(AV[12], wek[12].x, e0);\
    e0 = fmaf(AV[13], wek[13].x, e0); e0 = fmaf(AV[14], wek[14].x, e0);\
    e0 = fmaf(AV[15], wek[15].x, e0);                                  \
    float e1 = AV[0] * wek[0].y;                                       \
    e1 = fmaf(AV[1], wek[1].y, e1);   e1 = fmaf(AV[2], wek[2].y, e1);  \
    e1 = fmaf(AV[3], wek[3].y, e1);   e1 = fmaf(AV[4], wek[4].y, e1);  \
    e1 = fmaf(AV[5], wek[5].y, e1);   e1 = fmaf(AV[6], wek[6].y, e1);  \
    e1 = fmaf(AV[7], wek[7].y, e1);   e1 = fmaf(AV[8], wek[8].y, e1);  \
    e1 = fmaf(AV[9], wek[9].y, e1);   e1 = fmaf(AV[10], wek[10].y, e1);\
    e1 = fmaf(AV[11], wek[11].y, e1); e1 = fmaf(AV[12], wek[12].y, e1);\
    e1 = fmaf(AV[13], wek[13].y, e1); e1 = fmaf(AV[14], wek[14].y, e1);\
    e1 = fmaf(AV[15], wek[15].y, e1);                                  \
    es0 += e0; es1 += e1;                                              \
    float m0 = (XL.x + xr.x) + e0;                                     \
    float m1 = (XL.y + xr.y) + e1;                                     \
    float lm0 = fmaf(SLOPE, fminf(m0, 0.f), fmaxf(m0, 0.f));           \
    float lm1 = fmaf(SLOPE, fminf(m1, 0.f), fmaxf(m1, 0.f));           \
    float part = fmaf(attv.y, lm1, attv.x * lm0);                      \
    part += __shfl_xor(part, 1);                                       \
    part += __shfl_xor(part, 2);                                       \
    part += __shfl_xor(part, 4);                                       \
    part += __shfl_xor(part, 8);                                       \
    float p = __expf(part);                                            \
    lh += p;                                                           \
    acc0 = fmaf(p, XL.x, acc0);                                        \
    acc1 = fmaf(p, XL.y, acc1);                                        \
  }

__launch_bounds__(256)
__global__ void gat_kernel(const __half* __restrict__ x_l, const __half* __restrict__ x_r,
                           const int* __restrict__ rowptr, const int* __restrict__ csr_src,
                           const float* __restrict__ eattr_csr, const float* __restrict__ W_e,
                           const float* __restrict__ att, const float* __restrict__ bias,
                           float* __restrict__ out) {
  int wid = threadIdx.x >> 6;
  int lane = threadIdx.x & 63;
  int tbase = (blockIdx.x * 4 + wid) * 4;  // 3125*4*4 == 50000

  float2 wek[16];
#pragma unroll
  for (int k = 0; k < 16; ++k)
    wek[k] = *(const float2*)(W_e + k * 128 + 2 * lane);
  float2 attv = *(const float2*)(att + 2 * lane);
  float bv = bias[(2 * lane) & 31];
  float bv1 = bias[((2 * lane) & 31) + 1];

  for (int tt = 0; tt < 4; ++tt) {
    int t = tbase + tt;
    float2 xr = __half22float2(*(const __half2*)(x_r + (size_t)t * 128 + 2 * lane));
    int start = __builtin_amdgcn_readfirstlane(rowptr[t]);
    int end = __builtin_amdgcn_readfirstlane(rowptr[t + 1]);

    float lh = 0.f, acc0 = 0.f, acc1 = 0.f, es0 = 0.f, es1 = 0.f;

    int j = start;
    for (; j + 4 <= end; j += 4) {
      int s0 = __builtin_amdgcn_readfirstlane(csr_src[j]);
      int s1 = __builtin_amdgcn_readfirstlane(csr_src[j + 1]);
      int s2 = __builtin_amdgcn_readfirstlane(csr_src[j + 2]);
      int s3 = __builtin_amdgcn_readfirstlane(csr_src[j + 3]);
      float2 xl0 = __half22float2(*(const __half2*)(x_l + (size_t)s0 * 128 + 2 * lane));
      float2 xl1 = __half22float2(*(const __half2*)(x_l + (size_t)s1 * 128 + 2 * lane));
      float2 xl2 = __half22float2(*(const __half2*)(x_l + (size_t)s2 * 128 + 2 * lane));
      float2 xl3 = __half22float2(*(const __half2*)(x_l + (size_t)s3 * 128 + 2 * lane));
      const float* ap0 = eattr_csr + (size_t)j * 16;
      {
        float a0[16];
#pragma unroll
        for (int k = 0; k < 16; ++k) a0[k] = ap0[k];
        EDGE_PROC(a0, xl0)
      }
      {
        float a1[16];
#pragma unroll
        for (int k = 0; k < 16; ++k) a1[k] = ap0[16 + k];
        EDGE_PROC(a1, xl1)
      }
      {
        float a2[16];
#pragma unroll
        for (int k = 0; k < 16; ++k) a2[k] = ap0[32 + k];
        EDGE_PROC(a2, xl2)
      }
      {
        float a3[16];
#pragma unroll
        for (int k = 0; k < 16; ++k) a3[k] = ap0[48 + k];
        EDGE_PROC(a3, xl3)
      }
    }
    if (j + 2 <= end) {
      int s0 = __builtin_amdgcn_readfirstlane(csr_src[j]);
      int s1 = __builtin_amdgcn_readfirstlane(csr_src[j + 1]);
      float2 xl0 = __half22float2(*(const __half2*)(x_l + (size_t)s0 * 128 + 2 * lane));
      float2 xl1 = __half22float2(*(const __half2*)(x_l + (size_t)s1 * 128 + 2 * lane));
      const float* ap0 = eattr_csr + (size_t)j * 16;
      {
        float a0[16];
#pragma unroll
        for (int k = 0; k < 16; ++k) a0[k] = ap0[k];
        EDGE_PROC(a0, xl0)
      }
      {
        float a1[16];
#pragma unroll
        for (int k = 0; k < 16; ++k) a1[k] = ap0[16 + k];
        EDGE_PROC(a1, xl1)
      }
      j += 2;
    }
    if (j < end) {
      int srcn = __builtin_amdgcn_readfirstlane(csr_src[j]);
      const float* ap = eattr_csr + (size_t)j * 16;
      float aC[16];
#pragma unroll
      for (int k = 0; k < 16; ++k) aC[k] = ap[k];
      float2 xlC = __half22float2(*(const __half2*)(x_l + (size_t)srcn * 128 + 2 * lane));
      EDGE_PROC(aC, xlC)
    }

    // self-loop: e = es / max(deg,1); message source is x_l[t]
    {
      float rdeg = 1.0f / fmaxf((float)(end - start), 1.0f);
      float e0 = es0 * rdeg, e1 = es1 * rdeg;
      float2 xl = __half22float2(*(const __half2*)(x_l + (size_t)t * 128 + 2 * lane));
      float m0 = (xl.x + xr.x) + e0;
      float m1 = (xl.y + xr.y) + e1;
      float lm0 = fmaf(SLOPE, fminf(m0, 0.f), fmaxf(m0, 0.f));
      float lm1 = fmaf(SLOPE, fminf(m1, 0.f), fmaxf(m1, 0.f));
      float part = fmaf(attv.y, lm1, attv.x * lm0);
      part += __shfl_xor(part, 1);
      part += __shfl_xor(part, 2);
      part += __shfl_xor(part, 4);
      part += __shfl_xor(part, 8);
      float p = __expf(part);
      lh += p;
      acc0 = fmaf(p, xl.x, acc0);
      acc1 = fmaf(p, xl.y, acc1);
    }

    float inv = 1.0f / lh;
    float v0 = acc0 * inv, v1 = acc1 * inv;
    v0 += __shfl_xor(v0, 16);
    v0 += __shfl_xor(v0, 32);
    v1 += __shfl_xor(v1, 16);
    v1 += __shfl_xor(v1, 32);
    if (lane < 16) {
      float o0 = fmaf(v0, 0.25f, bv);
      float o1 = fmaf(v1, 0.25f, bv1);
      o0 = fmaf(SLOPE, fminf(o0, 0.f), fmaxf(o0, 0.f));
      o1 = fmaf(SLOPE, fminf(o1, 0.f), fmaxf(o1, 0.f));
      *(float2*)(out + (size_t)t * 32 + 2 * lane) = make_float2(o0, o1);
    }
  }
}

// ---------------- launch ----------------

extern "C" void kernel_launch(void* const* d_in, const int* in_sizes, int n_in,
                              void* d_out, int out_size, void* d_ws, size_t ws_size,
                              hipStream_t stream) {
  const float* x = (const float*)d_in[0];
  const int* ei = (const int*)d_in[1];
  const float* eattr = (const float*)d_in[2];
  const float* W_l = (const float*)d_in[3];
  const float* b_l = (const float*)d_in[4];
  const float* W_r = (const float*)d_in[5];
  const float* b_r = (const float*)d_in[6];
  const float* W_e = (const float*)d_in[7];
  const float* att = (const float*)d_in[8];
  const float* bias = (const float*)d_in[9];
  float* out = (float*)d_out;

  char* ws = (char*)d_ws;
  int* csr_src = (int*)ws;                       // 3,200,000 B
  float* eattr_csr = (float*)(ws + 3200000);     // 51,200,000 B
  __half* x_l = (__half*)(ws + 54400000);        // 12,800,000 B
  __half* x_r = (__half*)(ws + 67200000);        // 12,800,000 B
  int* deg = (int*)(ws + 80000000);              // 200,000 B
  int* rowptr = (int*)(ws + 80200000);           // 200,004 B
  int* rank = (int*)(ws + 80400016);             // 3,200,000 B
  int* psum = (int*)(ws + 83600016);             // 196 B

  hipMemsetAsync(deg, 0, NN * sizeof(int), stream);
  fusedA_kernel<<<GEMMB + EDGEB, 256, 0, stream>>>(x, W_l, b_l, x_l, ei + NE, deg, rank);
  partial_kernel<<<NB, 256, 0, stream>>>(deg, psum);
  final_kernel<<<NB, 256, 0, stream>>>(deg, psum, rowptr);
  fusedB_kernel<<<GEMMB + EDGEB, 256, 0, stream>>>(
      x, W_r, b_r, x_r, ei, ei + NE, rank, rowptr, (const float4*)eattr,
      csr_src, (float4*)eattr_csr);
  gat_kernel<<<NN / 16, 256, 0, stream>>>(x_l, x_r, rowptr, csr_src, eattr_csr, W_e, att, bias, out);
}

// Round 14
// 282.331 us; speedup vs baseline: 1.2138x; 1.0661x over previous
//
#include <hip/hip_runtime.h>
#include <hip/hip_fp16.h>
#include <math.h>

#define NN 50000
#define NE 800000
#define SLOPE 0.2f
#define NB 49        // ceil(50000 / 1024)
#define GEMMB 782    // ceil(50000 / 64) gemm blocks per side
#define EDGEB 3125   // ceil(800000 / 256) edge-parallel blocks

typedef __attribute__((ext_vector_type(8))) short bf16x8;
typedef __attribute__((ext_vector_type(4))) float f32x4;
typedef _Float16 half2v __attribute__((ext_vector_type(2)));

// v_dot2_f32_f16: 2 fp16 products, fp32 accumulate (precision-safe dot)
#if __has_builtin(__builtin_amdgcn_fdot2)
#define FDOT2(A, B, C) __builtin_amdgcn_fdot2((A), (B), (C), false)
#else
#define FDOT2(A, B, C) \
  fmaf((float)(A).x, (float)(B).x, fmaf((float)(A).y, (float)(B).y, (C)))
#endif

// split fp32 into two bf16 halves: v ~= hi + lo, residual ~2^-16 * |v|.
static __device__ __forceinline__ void split_bf16(float v, unsigned short& h,
                                                  unsigned short& l) {
  unsigned u = __float_as_uint(v);
  h = (unsigned short)(u >> 16);
  float hf = __uint_as_float(((unsigned)h) << 16);
  float r = v - hf;
  l = (unsigned short)(__float_as_uint(r) >> 16);
}

// ---------------- MFMA split-bf16 gemm body (r10-proven) ----------------
// 64 nodes x 128 cols per block, K=128 in 4 chunks of 32. 4 waves, each owns a
// 16-row strip. C = xh@wh + xl@wh + xh@wl on the matrix pipe. Output fp16.
//   A: row=lane&15, k=8*(lane>>4)+i   B: col=lane&15, same k
//   C: col=lane&15, row=4*(lane>>4)+reg

__device__ __forceinline__ void gemm_body(int bx, const float* __restrict__ x,
                                          const float* __restrict__ W,
                                          const float* __restrict__ bptr,
                                          __half* __restrict__ optr,
                                          unsigned short* xh_s, unsigned short* xl_s,
                                          unsigned short* wh_s, unsigned short* wl_s) {
  int tid = threadIdx.x;
  int w = tid >> 6;
  int l = tid & 63;
  int n0 = bx * 64;

  f32x4 acc[8];
#pragma unroll
  for (int i = 0; i < 8; ++i) acc[i] = (f32x4){0.f, 0.f, 0.f, 0.f};

  for (int kb = 0; kb < 128; kb += 32) {
    // stage x chunk (64 rows x 32 k) as split-bf16, row stride 40 (pad)
    {
      int row = tid >> 2;
      int kc = (tid & 3) * 8;
      int gn = n0 + row;
      float4 v0 = make_float4(0.f, 0.f, 0.f, 0.f);
      float4 v1 = make_float4(0.f, 0.f, 0.f, 0.f);
      if (gn < NN) {
        v0 = *(const float4*)(x + (size_t)gn * 128 + kb + kc);
        v1 = *(const float4*)(x + (size_t)gn * 128 + kb + kc + 4);
      }
      unsigned short h[8], lo[8];
      split_bf16(v0.x, h[0], lo[0]); split_bf16(v0.y, h[1], lo[1]);
      split_bf16(v0.z, h[2], lo[2]); split_bf16(v0.w, h[3], lo[3]);
      split_bf16(v1.x, h[4], lo[4]); split_bf16(v1.y, h[5], lo[5]);
      split_bf16(v1.z, h[6], lo[6]); split_bf16(v1.w, h[7], lo[7]);
      bf16x8 hv, lv;
#pragma unroll
      for (int i = 0; i < 8; ++i) { hv[i] = (short)h[i]; lv[i] = (short)lo[i]; }
      *(bf16x8*)&xh_s[row * 40 + kc] = hv;
      *(bf16x8*)&xl_s[row * 40 + kc] = lv;
    }
    // stage W chunk TRANSPOSED (col-major for B frags), stride 40
    {
      int col = tid & 127;
      int kk0 = (tid >> 7) * 16;
      unsigned short h[16], lo[16];
#pragma unroll
      for (int j = 0; j < 16; ++j)
        split_bf16(W[(size_t)(kb + kk0 + j) * 128 + col], h[j], lo[j]);
      bf16x8 hv0, hv1, lv0, lv1;
#pragma unroll
      for (int i = 0; i < 8; ++i) {
        hv0[i] = (short)h[i]; hv1[i] = (short)h[8 + i];
        lv0[i] = (short)lo[i]; lv1[i] = (short)lo[8 + i];
      }
      *(bf16x8*)&wh_s[col * 40 + kk0] = hv0;
      *(bf16x8*)&wh_s[col * 40 + kk0 + 8] = hv1;
      *(bf16x8*)&wl_s[col * 40 + kk0] = lv0;
      *(bf16x8*)&wl_s[col * 40 + kk0 + 8] = lv1;
    }
    __syncthreads();

    int r16 = 16 * w + (l & 15);
    int ko = (l >> 4) * 8;
    bf16x8 ah = *(bf16x8*)&xh_s[r16 * 40 + ko];
    bf16x8 al = *(bf16x8*)&xl_s[r16 * 40 + ko];
#pragma unroll
    for (int ct = 0; ct < 8; ++ct) {
      int cbase = (ct * 16 + (l & 15)) * 40 + ko;
      bf16x8 bh = *(bf16x8*)&wh_s[cbase];
      bf16x8 bl = *(bf16x8*)&wl_s[cbase];
      acc[ct] = __builtin_amdgcn_mfma_f32_16x16x32_bf16(ah, bh, acc[ct], 0, 0, 0);
      acc[ct] = __builtin_amdgcn_mfma_f32_16x16x32_bf16(al, bh, acc[ct], 0, 0, 0);
      acc[ct] = __builtin_amdgcn_mfma_f32_16x16x32_bf16(ah, bl, acc[ct], 0, 0, 0);
    }
    __syncthreads();
  }

  // epilogue: lane covers col=l&15, rows 4*(l>>4)+r; store fp16
  int colb = l & 15;
  int rq = (l >> 4) * 4;
#pragma unroll
  for (int ct = 0; ct < 8; ++ct) {
    float bvv = bptr[ct * 16 + colb];
#pragma unroll
    for (int r = 0; r < 4; ++r) {
      int gn = n0 + 16 * w + rq + r;
      if (gn < NN)
        optr[(size_t)gn * 128 + ct * 16 + colb] = __float2half(acc[ct][r] + bvv);
    }
  }
}

// ---------------- fused launch A: gemm_L (MFMA) + deg/rank ----------------

__launch_bounds__(256)
__global__ void fusedA_kernel(const float* __restrict__ x,
                              const float* __restrict__ W_l, const float* __restrict__ b_l,
                              __half* __restrict__ x_l,
                              const int* __restrict__ tgt, int* __restrict__ deg,
                              int* __restrict__ rank) {
  __shared__ unsigned short xh_s[64 * 40], xl_s[64 * 40];
  __shared__ unsigned short wh_s[128 * 40], wl_s[128 * 40];
  if (blockIdx.x < GEMMB) {
    gemm_body(blockIdx.x, x, W_l, b_l, x_l, xh_s, xl_s, wh_s, wl_s);
  } else {
    int e = (blockIdx.x - GEMMB) * 256 + threadIdx.x;
    if (e < NE) rank[e] = atomicAdd(&deg[tgt[e]], 1);
  }
}

// ---------------- fused launch B: gemm_R (MFMA) + atomic-free scatter ----------------
// Scatter now converts the 64B fp32 attr row to a 32B fp16 row: halves the
// random write-line traffic AND gat's attr stream; enables fdot2 in gat.

__launch_bounds__(256)
__global__ void fusedB_kernel(const float* __restrict__ x,
                              const float* __restrict__ W_r, const float* __restrict__ b_r,
                              __half* __restrict__ x_r,
                              const int* __restrict__ src, const int* __restrict__ tgt,
                              const int* __restrict__ rank,
                              const int* __restrict__ rowptr,
                              const float4* __restrict__ eattr4,
                              int* __restrict__ csr_src,
                              unsigned short* __restrict__ eattr_h) {
  __shared__ unsigned short xh_s[64 * 40], xl_s[64 * 40];
  __shared__ unsigned short wh_s[128 * 40], wl_s[128 * 40];
  if (blockIdx.x < GEMMB) {
    gemm_body(blockIdx.x, x, W_r, b_r, x_r, xh_s, xl_s, wh_s, wl_s);
  } else {
    int e = (blockIdx.x - GEMMB) * 256 + threadIdx.x;
    if (e < NE) {
      int t = tgt[e];
      int r = rank[e];
      float4 a0 = eattr4[(size_t)e * 4 + 0];
      float4 a1 = eattr4[(size_t)e * 4 + 1];
      float4 a2 = eattr4[(size_t)e * 4 + 2];
      float4 a3 = eattr4[(size_t)e * 4 + 3];
      __half2 q0 = __float22half2_rn(make_float2(a0.x, a0.y));
      __half2 q1 = __float22half2_rn(make_float2(a0.z, a0.w));
      __half2 q2 = __float22half2_rn(make_float2(a1.x, a1.y));
      __half2 q3 = __float22half2_rn(make_float2(a1.z, a1.w));
      __half2 q4 = __float22half2_rn(make_float2(a2.x, a2.y));
      __half2 q5 = __float22half2_rn(make_float2(a2.z, a2.w));
      __half2 q6 = __float22half2_rn(make_float2(a3.x, a3.y));
      __half2 q7 = __float22half2_rn(make_float2(a3.z, a3.w));
      uint4 u0, u1;
      u0.x = __builtin_bit_cast(unsigned, q0); u0.y = __builtin_bit_cast(unsigned, q1);
      u0.z = __builtin_bit_cast(unsigned, q2); u0.w = __builtin_bit_cast(unsigned, q3);
      u1.x = __builtin_bit_cast(unsigned, q4); u1.y = __builtin_bit_cast(unsigned, q5);
      u1.z = __builtin_bit_cast(unsigned, q6); u1.w = __builtin_bit_cast(unsigned, q7);
      int pos = rowptr[t] + r;
      csr_src[pos] = src[e];
      unsigned short* row = eattr_h + (size_t)pos * 16;
      *(uint4*)row = u0;
      *(uint4*)(row + 8) = u1;
    }
  }
}

// ---------------- CSR prefix-scan (2 kernels) ----------------

__global__ void partial_kernel(const int* __restrict__ deg, int* __restrict__ psum) {
  int b = blockIdx.x;
  int base = b * 1024 + threadIdx.x * 4;
  int s = 0;
  if (base + 3 < NN) {
    int4 v = *(const int4*)(deg + base);
    s = v.x + v.y + v.z + v.w;
  } else {
#pragma unroll
    for (int i = 0; i < 4; ++i)
      if (base + i < NN) s += deg[base + i];
  }
  s += __shfl_xor(s, 1);
  s += __shfl_xor(s, 2);
  s += __shfl_xor(s, 4);
  s += __shfl_xor(s, 8);
  s += __shfl_xor(s, 16);
  s += __shfl_xor(s, 32);
  __shared__ int wsum[4];
  if ((threadIdx.x & 63) == 0) wsum[threadIdx.x >> 6] = s;
  __syncthreads();
  if (threadIdx.x == 0) psum[b] = wsum[0] + wsum[1] + wsum[2] + wsum[3];
}

// Each block redundantly wave-scans the 49 psums -> no separate scanpart launch.
__global__ void final_kernel(const int* __restrict__ deg, const int* __restrict__ psum,
                             int* __restrict__ rowptr) {
  __shared__ int offs_s;
  __shared__ int wtot[4];
  int b = blockIdx.x;
  int t = threadIdx.x;
  if (t < 64) {
    int lane = t;
    int mine = (lane < NB) ? psum[lane] : 0;
    int v = mine;
#pragma unroll
    for (int off = 1; off < 64; off <<= 1) {
      int u = __shfl_up(v, off);
      if (lane >= off) v += u;
    }
    if (lane == b) offs_s = v - mine;          // this block's exclusive offset
    if (b == 0 && lane == 63) rowptr[NN] = v;  // grand total
  }
  __syncthreads();

  int base = b * 1024 + t * 4;
  int d0 = 0, d1 = 0, d2 = 0, d3 = 0;
  if (base + 3 < NN) {
    int4 v = *(const int4*)(deg + base);
    d0 = v.x; d1 = v.y; d2 = v.z; d3 = v.w;
  } else {
    if (base < NN) d0 = deg[base];
    if (base + 1 < NN) d1 = deg[base + 1];
    if (base + 2 < NN) d2 = deg[base + 2];
  }
  int s = d0 + d1 + d2 + d3;
  int lane = t & 63, w = t >> 6;
  int v = s;
#pragma unroll
  for (int off = 1; off < 64; off <<= 1) {
    int u = __shfl_up(v, off);
    if (lane >= off) v += u;
  }
  if (lane == 63) wtot[w] = v;
  __syncthreads();
  int woff = 0;
#pragma unroll
  for (int i = 0; i < 4; ++i)
    if (i < w) woff += wtot[i];
  int run = offs_s + woff + (v - s);
  if (base < NN)     { rowptr[base] = run;     run += d0; }
  if (base + 1 < NN) { rowptr[base + 1] = run; run += d1; }
  if (base + 2 < NN) { rowptr[base + 2] = run; run += d2; }
  if (base + 3 < NN) { rowptr[base + 3] = run; }
}

// ---------------- main GATv2 kernel ----------------
// One wave per 4 consecutive targets; lane L holds channels (2L, 2L+1).
// Attrs pre-gathered into CSR order as FP16 (32B rows, induction-based
// s_loads). Per-channel W_e dot = 8x v_dot2_f32_f16 (fp16 mul, fp32 acc):
// 16 insts/edge vs 32 fp32 fma -- gat was AT its VALU floor (r13: busy 63us
// of 103us wall, fetch halving changed nothing).

#define EDGE_PROC_H(AU, XL)                                            \
  {                                                                    \
    float e0 = 0.f, e1 = 0.f;                                          \
    _Pragma("unroll")                                                  \
    for (int jj = 0; jj < 8; ++jj) {                                   \
      half2v ha = __builtin_bit_cast(half2v, AU[jj]);                  \
      e0 = FDOT2(ha, wekA[jj], e0);                                    \
      e1 = FDOT2(ha, wekB[jj], e1);                                    \
    }                                                                  \
    es0 += e0; es1 += e1;                                              \
    float m0 = (XL.x + xr.x) + e0;                                     \
    float m1 = (XL.y + xr.y) + e1;                                     \
    float lm0 = fmaf(SLOPE, fminf(m0, 0.f), fmaxf(m0, 0.f));           \
    float lm1 = fmaf(SLOPE, fminf(m1, 0.f), fmaxf(m1, 0.f));           \
    float part = fmaf(attv.y, lm1, attv.x * lm0);                      \
    part += __shfl_xor(part, 1);                                       \
    part += __shfl_xor(part, 2);                                       \
    part += __shfl_xor(part, 4);                                       \
    part += __shfl_xor(part, 8);                                       \
    float p = __expf(part);                                            \
    lh += p;                                                           \
    acc0 = fmaf(p, XL.x, acc0);                                        \
    acc1 = fmaf(p, XL.y, acc1);                                        \
  }

__launch_bounds__(256)
__global__ void gat_kernel(const __half* __restrict__ x_l, const __half* __restrict__ x_r,
                           const int* __restrict__ rowptr, const int* __restrict__ csr_src,
                           const unsigned short* __restrict__ eattr_h,
                           const float* __restrict__ W_e,
                           const float* __restrict__ att, const float* __restrict__ bias,
                           float* __restrict__ out) {
  int wid = threadIdx.x >> 6;
  int lane = threadIdx.x & 63;
  int tbase = (blockIdx.x * 4 + wid) * 4;  // 3125*4*4 == 50000

  // wek as fp16 k-pairs: wekA[j] = (W_e[2j][2L], W_e[2j+1][2L]), wekB for 2L+1
  half2v wekA[8], wekB[8];
#pragma unroll
  for (int j = 0; j < 8; ++j) {
    float2 w0 = *(const float2*)(W_e + (2 * j) * 128 + 2 * lane);
    float2 w1 = *(const float2*)(W_e + (2 * j + 1) * 128 + 2 * lane);
    wekA[j].x = (_Float16)w0.x; wekA[j].y = (_Float16)w1.x;
    wekB[j].x = (_Float16)w0.y; wekB[j].y = (_Float16)w1.y;
  }
  float2 attv = *(const float2*)(att + 2 * lane);
  float bv = bias[(2 * lane) & 31];
  float bv1 = bias[((2 * lane) & 31) + 1];

  for (int tt = 0; tt < 4; ++tt) {
    int t = tbase + tt;
    float2 xr = __half22float2(*(const __half2*)(x_r + (size_t)t * 128 + 2 * lane));
    int start = __builtin_amdgcn_readfirstlane(rowptr[t]);
    int end = __builtin_amdgcn_readfirstlane(rowptr[t + 1]);

    float lh = 0.f, acc0 = 0.f, acc1 = 0.f, es0 = 0.f, es1 = 0.f;

    int j = start;
    for (; j + 4 <= end; j += 4) {
      int s0 = __builtin_amdgcn_readfirstlane(csr_src[j]);
      int s1 = __builtin_amdgcn_readfirstlane(csr_src[j + 1]);
      int s2 = __builtin_amdgcn_readfirstlane(csr_src[j + 2]);
      int s3 = __builtin_amdgcn_readfirstlane(csr_src[j + 3]);
      float2 xl0 = __half22float2(*(const __half2*)(x_l + (size_t)s0 * 128 + 2 * lane));
      float2 xl1 = __half22float2(*(const __half2*)(x_l + (size_t)s1 * 128 + 2 * lane));
      float2 xl2 = __half22float2(*(const __half2*)(x_l + (size_t)s2 * 128 + 2 * lane));
      float2 xl3 = __half22float2(*(const __half2*)(x_l + (size_t)s3 * 128 + 2 * lane));
      const unsigned* apg = (const unsigned*)eattr_h + (size_t)j * 8;
      unsigned A0[8], A1[8], A2[8], A3[8];
#pragma unroll
      for (int k = 0; k < 8; ++k) A0[k] = apg[k];
#pragma unroll
      for (int k = 0; k < 8; ++k) A1[k] = apg[8 + k];
#pragma unroll
      for (int k = 0; k < 8; ++k) A2[k] = apg[16 + k];
#pragma unroll
      for (int k = 0; k < 8; ++k) A3[k] = apg[24 + k];
      EDGE_PROC_H(A0, xl0)
      EDGE_PROC_H(A1, xl1)
      EDGE_PROC_H(A2, xl2)
      EDGE_PROC_H(A3, xl3)
    }
    if (j + 2 <= end) {
      int s0 = __builtin_amdgcn_readfirstlane(csr_src[j]);
      int s1 = __builtin_amdgcn_readfirstlane(csr_src[j + 1]);
      float2 xl0 = __half22float2(*(const __half2*)(x_l + (size_t)s0 * 128 + 2 * lane));
      float2 xl1 = __half22float2(*(const __half2*)(x_l + (size_t)s1 * 128 + 2 * lane));
      const unsigned* apg = (const unsigned*)eattr_h + (size_t)j * 8;
      unsigned A0[8], A1[8];
#pragma unroll
      for (int k = 0; k < 8; ++k) A0[k] = apg[k];
#pragma unroll
      for (int k = 0; k < 8; ++k) A1[k] = apg[8 + k];
      EDGE_PROC_H(A0, xl0)
      EDGE_PROC_H(A1, xl1)
      j += 2;
    }
    if (j < end) {
      int srcn = __builtin_amdgcn_readfirstlane(csr_src[j]);
      float2 xlC = __half22float2(*(const __half2*)(x_l + (size_t)srcn * 128 + 2 * lane));
      const unsigned* apg = (const unsigned*)eattr_h + (size_t)j * 8;
      unsigned A0[8];
#pragma unroll
      for (int k = 0; k < 8; ++k) A0[k] = apg[k];
      EDGE_PROC_H(A0, xlC)
    }

    // self-loop: e = es / max(deg,1); message source is x_l[t]
    {
      float rdeg = 1.0f / fmaxf((float)(end - start), 1.0f);
      float e0 = es0 * rdeg, e1 = es1 * rdeg;
      float2 xl = __half22float2(*(const __half2*)(x_l + (size_t)t * 128 + 2 * lane));
      float m0 = (xl.x + xr.x) + e0;
      float m1 = (xl.y + xr.y) + e1;
      float lm0 = fmaf(SLOPE, fminf(m0, 0.f), fmaxf(m0, 0.f));
      float lm1 = fmaf(SLOPE, fminf(m1, 0.f), fmaxf(m1, 0.f));
      float part = fmaf(attv.y, lm1, attv.x * lm0);
      part += __shfl_xor(part, 1);
      part += __shfl_xor(part, 2);
      part += __shfl_xor(part, 4);
      part += __shfl_xor(part, 8);
      float p = __expf(part);
      lh += p;
      acc0 = fmaf(p, xl.x, acc0);
      acc1 = fmaf(p, xl.y, acc1);
    }

    float inv = 1.0f / lh;
    float v0 = acc0 * inv, v1 = acc1 * inv;
    v0 += __shfl_xor(v0, 16);
    v0 += __shfl_xor(v0, 32);
    v1 += __shfl_xor(v1, 16);
    v1 += __shfl_xor(v1, 32);
    if (lane < 16) {
      float o0 = fmaf(v0, 0.25f, bv);
      float o1 = fmaf(v1, 0.25f, bv1);
      o0 = fmaf(SLOPE, fminf(o0, 0.f), fmaxf(o0, 0.f));
      o1 = fmaf(SLOPE, fminf(o1, 0.f), fmaxf(o1, 0.f));
      *(float2*)(out + (size_t)t * 32 + 2 * lane) = make_float2(o0, o1);
    }
  }
}

// ---------------- launch ----------------

extern "C" void kernel_launch(void* const* d_in, const int* in_sizes, int n_in,
                              void* d_out, int out_size, void* d_ws, size_t ws_size,
                              hipStream_t stream) {
  const float* x = (const float*)d_in[0];
  const int* ei = (const int*)d_in[1];
  const float* eattr = (const float*)d_in[2];
  const float* W_l = (const float*)d_in[3];
  const float* b_l = (const float*)d_in[4];
  const float* W_r = (const float*)d_in[5];
  const float* b_r = (const float*)d_in[6];
  const float* W_e = (const float*)d_in[7];
  const float* att = (const float*)d_in[8];
  const float* bias = (const float*)d_in[9];
  float* out = (float*)d_out;

  char* ws = (char*)d_ws;
  int* csr_src = (int*)ws;                            // 3,200,000 B
  unsigned short* eattr_h = (unsigned short*)(ws + 3200000);  // 25,600,000 B
  __half* x_l = (__half*)(ws + 28800000);             // 12,800,000 B
  __half* x_r = (__half*)(ws + 41600000);             // 12,800,000 B
  int* deg = (int*)(ws + 54400000);                   // 200,000 B
  int* rowptr = (int*)(ws + 54600000);                // 200,004 B
  int* rank = (int*)(ws + 54800016);                  // 3,200,000 B
  int* psum = (int*)(ws + 58000016);                  // 196 B

  hipMemsetAsync(deg, 0, NN * sizeof(int), stream);
  fusedA_kernel<<<GEMMB + EDGEB, 256, 0, stream>>>(x, W_l, b_l, x_l, ei + NE, deg, rank);
  partial_kernel<<<NB, 256, 0, stream>>>(deg, psum);
  final_kernel<<<NB, 256, 0, stream>>>(deg, psum, rowptr);
  fusedB_kernel<<<GEMMB + EDGEB, 256, 0, stream>>>(
      x, W_r, b_r, x_r, ei, ei + NE, rank, rowptr, (const float4*)eattr,
      csr_src, eattr_h);
  gat_kernel<<<NN / 16, 256, 0, stream>>>(x_l, x_r, rowptr, csr_src, eattr_h, W_e, att, bias, out);
}

// Round 15
// 280.503 us; speedup vs baseline: 1.2217x; 1.0065x over previous
//
#include <hip/hip_runtime.h>
#include <hip/hip_fp16.h>
#include <math.h>

#define NN 50000
#define NE 800000
#define SLOPE 0.2f
#define NB 49        // ceil(50000 / 1024)
#define GEMMB 782    // ceil(50000 / 64) gemm blocks per side
#define EDGEB 3125   // ceil(800000 / 256) edge-parallel blocks

typedef __attribute__((ext_vector_type(8))) short bf16x8;
typedef __attribute__((ext_vector_type(4))) float f32x4;
typedef _Float16 half2v __attribute__((ext_vector_type(2)));

// v_dot2_f32_f16: 2 fp16 products, fp32 accumulate (precision-safe dot)
#if __has_builtin(__builtin_amdgcn_fdot2)
#define FDOT2(A, B, C) __builtin_amdgcn_fdot2((A), (B), (C), false)
#else
#define FDOT2(A, B, C) \
  fmaf((float)(A).x, (float)(B).x, fmaf((float)(A).y, (float)(B).y, (C)))
#endif

// split fp32 into two bf16 halves: v ~= hi + lo, residual ~2^-16 * |v|.
static __device__ __forceinline__ void split_bf16(float v, unsigned short& h,
                                                  unsigned short& l) {
  unsigned u = __float_as_uint(v);
  h = (unsigned short)(u >> 16);
  float hf = __uint_as_float(((unsigned)h) << 16);
  float r = v - hf;
  l = (unsigned short)(__float_as_uint(r) >> 16);
}

// ---------------- MFMA split-bf16 gemm body (r10-proven) ----------------
// 64 nodes x 128 cols per block, K=128 in 4 chunks of 32. 4 waves, each owns a
// 16-row strip. C = xh@wh + xl@wh + xh@wl on the matrix pipe. Output fp16.
//   A: row=lane&15, k=8*(lane>>4)+i   B: col=lane&15, same k
//   C: col=lane&15, row=4*(lane>>4)+reg

__device__ __forceinline__ void gemm_body(int bx, const float* __restrict__ x,
                                          const float* __restrict__ W,
                                          const float* __restrict__ bptr,
                                          __half* __restrict__ optr,
                                          unsigned short* xh_s, unsigned short* xl_s,
                                          unsigned short* wh_s, unsigned short* wl_s) {
  int tid = threadIdx.x;
  int w = tid >> 6;
  int l = tid & 63;
  int n0 = bx * 64;

  f32x4 acc[8];
#pragma unroll
  for (int i = 0; i < 8; ++i) acc[i] = (f32x4){0.f, 0.f, 0.f, 0.f};

  for (int kb = 0; kb < 128; kb += 32) {
    // stage x chunk (64 rows x 32 k) as split-bf16, row stride 40 (pad)
    {
      int row = tid >> 2;
      int kc = (tid & 3) * 8;
      int gn = n0 + row;
      float4 v0 = make_float4(0.f, 0.f, 0.f, 0.f);
      float4 v1 = make_float4(0.f, 0.f, 0.f, 0.f);
      if (gn < NN) {
        v0 = *(const float4*)(x + (size_t)gn * 128 + kb + kc);
        v1 = *(const float4*)(x + (size_t)gn * 128 + kb + kc + 4);
      }
      unsigned short h[8], lo[8];
      split_bf16(v0.x, h[0], lo[0]); split_bf16(v0.y, h[1], lo[1]);
      split_bf16(v0.z, h[2], lo[2]); split_bf16(v0.w, h[3], lo[3]);
      split_bf16(v1.x, h[4], lo[4]); split_bf16(v1.y, h[5], lo[5]);
      split_bf16(v1.z, h[6], lo[6]); split_bf16(v1.w, h[7], lo[7]);
      bf16x8 hv, lv;
#pragma unroll
      for (int i = 0; i < 8; ++i) { hv[i] = (short)h[i]; lv[i] = (short)lo[i]; }
      *(bf16x8*)&xh_s[row * 40 + kc] = hv;
      *(bf16x8*)&xl_s[row * 40 + kc] = lv;
    }
    // stage W chunk TRANSPOSED (col-major for B frags), stride 40
    {
      int col = tid & 127;
      int kk0 = (tid >> 7) * 16;
      unsigned short h[16], lo[16];
#pragma unroll
      for (int j = 0; j < 16; ++j)
        split_bf16(W[(size_t)(kb + kk0 + j) * 128 + col], h[j], lo[j]);
      bf16x8 hv0, hv1, lv0, lv1;
#pragma unroll
      for (int i = 0; i < 8; ++i) {
        hv0[i] = (short)h[i]; hv1[i] = (short)h[8 + i];
        lv0[i] = (short)lo[i]; lv1[i] = (short)lo[8 + i];
      }
      *(bf16x8*)&wh_s[col * 40 + kk0] = hv0;
      *(bf16x8*)&wh_s[col * 40 + kk0 + 8] = hv1;
      *(bf16x8*)&wl_s[col * 40 + kk0] = lv0;
      *(bf16x8*)&wl_s[col * 40 + kk0 + 8] = lv1;
    }
    __syncthreads();

    int r16 = 16 * w + (l & 15);
    int ko = (l >> 4) * 8;
    bf16x8 ah = *(bf16x8*)&xh_s[r16 * 40 + ko];
    bf16x8 al = *(bf16x8*)&xl_s[r16 * 40 + ko];
#pragma unroll
    for (int ct = 0; ct < 8; ++ct) {
      int cbase = (ct * 16 + (l & 15)) * 40 + ko;
      bf16x8 bh = *(bf16x8*)&wh_s[cbase];
      bf16x8 bl = *(bf16x8*)&wl_s[cbase];
      acc[ct] = __builtin_amdgcn_mfma_f32_16x16x32_bf16(ah, bh, acc[ct], 0, 0, 0);
      acc[ct] = __builtin_amdgcn_mfma_f32_16x16x32_bf16(al, bh, acc[ct], 0, 0, 0);
      acc[ct] = __builtin_amdgcn_mfma_f32_16x16x32_bf16(ah, bl, acc[ct], 0, 0, 0);
    }
    __syncthreads();
  }

  // epilogue: lane covers col=l&15, rows 4*(l>>4)+r; store fp16
  int colb = l & 15;
  int rq = (l >> 4) * 4;
#pragma unroll
  for (int ct = 0; ct < 8; ++ct) {
    float bvv = bptr[ct * 16 + colb];
#pragma unroll
    for (int r = 0; r < 4; ++r) {
      int gn = n0 + 16 * w + rq + r;
      if (gn < NN)
        optr[(size_t)gn * 128 + ct * 16 + colb] = __float2half(acc[ct][r] + bvv);
    }
  }
}

// ---------------- fused launch A: gemm_L (MFMA) + XCD-bucketed deg/rank ----------------
// deg8[bucket][node] with bucket = blockIdx & 7 (~XCD under round-robin
// dispatch): a node's count line receives atomics from ONE XCD only -- no
// cross-L2 ping-pong. Correctness does not depend on the bucket<->XCD mapping
// (any consistent partition works). rank packs (bucket, local_rank).

__launch_bounds__(256)
__global__ void fusedA_kernel(const float* __restrict__ x,
                              const float* __restrict__ W_l, const float* __restrict__ b_l,
                              __half* __restrict__ x_l,
                              const int* __restrict__ tgt, int* __restrict__ deg8,
                              int* __restrict__ rank) {
  __shared__ unsigned short xh_s[64 * 40], xl_s[64 * 40];
  __shared__ unsigned short wh_s[128 * 40], wl_s[128 * 40];
  if (blockIdx.x < GEMMB) {
    gemm_body(blockIdx.x, x, W_l, b_l, x_l, xh_s, xl_s, wh_s, wl_s);
  } else {
    int e = (blockIdx.x - GEMMB) * 256 + threadIdx.x;
    if (e < NE) {
      int bkt = blockIdx.x & 7;
      int r = atomicAdd(&deg8[bkt * NN + tgt[e]], 1);
      rank[e] = (bkt << 24) | r;
    }
  }
}

// ---------------- fused launch B: gemm_R (MFMA) + atomic-free scatter ----------------
// pos = xoffabs[bucket][t] + local_rank (single random read; no rowptr).
// Converts the 64B fp32 attr row to a 32B fp16 row for gat's fdot2 path.

__launch_bounds__(256)
__global__ void fusedB_kernel(const float* __restrict__ x,
                              const float* __restrict__ W_r, const float* __restrict__ b_r,
                              __half* __restrict__ x_r,
                              const int* __restrict__ src, const int* __restrict__ tgt,
                              const int* __restrict__ rank,
                              const int* __restrict__ xoffabs,
                              const float4* __restrict__ eattr4,
                              int* __restrict__ csr_src,
                              unsigned short* __restrict__ eattr_h) {
  __shared__ unsigned short xh_s[64 * 40], xl_s[64 * 40];
  __shared__ unsigned short wh_s[128 * 40], wl_s[128 * 40];
  if (blockIdx.x < GEMMB) {
    gemm_body(blockIdx.x, x, W_r, b_r, x_r, xh_s, xl_s, wh_s, wl_s);
  } else {
    int e = (blockIdx.x - GEMMB) * 256 + threadIdx.x;
    if (e < NE) {
      int t = tgt[e];
      int rr = rank[e];
      int bkt = rr >> 24;
      int r = rr & 0xFFFFFF;
      float4 a0 = eattr4[(size_t)e * 4 + 0];
      float4 a1 = eattr4[(size_t)e * 4 + 1];
      float4 a2 = eattr4[(size_t)e * 4 + 2];
      float4 a3 = eattr4[(size_t)e * 4 + 3];
      __half2 q0 = __float22half2_rn(make_float2(a0.x, a0.y));
      __half2 q1 = __float22half2_rn(make_float2(a0.z, a0.w));
      __half2 q2 = __float22half2_rn(make_float2(a1.x, a1.y));
      __half2 q3 = __float22half2_rn(make_float2(a1.z, a1.w));
      __half2 q4 = __float22half2_rn(make_float2(a2.x, a2.y));
      __half2 q5 = __float22half2_rn(make_float2(a2.z, a2.w));
      __half2 q6 = __float22half2_rn(make_float2(a3.x, a3.y));
      __half2 q7 = __float22half2_rn(make_float2(a3.z, a3.w));
      uint4 u0, u1;
      u0.x = __builtin_bit_cast(unsigned, q0); u0.y = __builtin_bit_cast(unsigned, q1);
      u0.z = __builtin_bit_cast(unsigned, q2); u0.w = __builtin_bit_cast(unsigned, q3);
      u1.x = __builtin_bit_cast(unsigned, q4); u1.y = __builtin_bit_cast(unsigned, q5);
      u1.z = __builtin_bit_cast(unsigned, q6); u1.w = __builtin_bit_cast(unsigned, q7);
      int pos = xoffabs[bkt * NN + t] + r;
      csr_src[pos] = src[e];
      unsigned short* row = eattr_h + (size_t)pos * 16;
      *(uint4*)row = u0;
      *(uint4*)(row + 8) = u1;
    }
  }
}

// ---------------- CSR prefix-scan over bucketed counts (2 kernels) ----------------

__global__ void partial_kernel(const int* __restrict__ deg8, int* __restrict__ psum) {
  int b = blockIdx.x;
  int base = b * 1024 + threadIdx.x * 4;
  int s = 0;
  if (base + 3 < NN) {
#pragma unroll
    for (int xcd = 0; xcd < 8; ++xcd) {
      int4 v = *(const int4*)(deg8 + (size_t)xcd * NN + base);
      s += v.x + v.y + v.z + v.w;
    }
  } else {
#pragma unroll
    for (int i = 0; i < 4; ++i)
      if (base + i < NN)
#pragma unroll
        for (int xcd = 0; xcd < 8; ++xcd) s += deg8[(size_t)xcd * NN + base + i];
  }
  s += __shfl_xor(s, 1);
  s += __shfl_xor(s, 2);
  s += __shfl_xor(s, 4);
  s += __shfl_xor(s, 8);
  s += __shfl_xor(s, 16);
  s += __shfl_xor(s, 32);
  __shared__ int wsum[4];
  if ((threadIdx.x & 63) == 0) wsum[threadIdx.x >> 6] = s;
  __syncthreads();
  if (threadIdx.x == 0) psum[b] = wsum[0] + wsum[1] + wsum[2] + wsum[3];
}

// Each block redundantly wave-scans the 49 psums; writes rowptr AND the
// per-node per-bucket absolute offsets xoffabs[x][t] = rowptr[t] + prefix_x.
__global__ void final_kernel(const int* __restrict__ deg8, const int* __restrict__ psum,
                             int* __restrict__ rowptr, int* __restrict__ xoffabs) {
  __shared__ int offs_s;
  __shared__ int wtot[4];
  int b = blockIdx.x;
  int t = threadIdx.x;
  if (t < 64) {
    int lane = t;
    int mine = (lane < NB) ? psum[lane] : 0;
    int v = mine;
#pragma unroll
    for (int off = 1; off < 64; off <<= 1) {
      int u = __shfl_up(v, off);
      if (lane >= off) v += u;
    }
    if (lane == b) offs_s = v - mine;          // this block's exclusive offset
    if (b == 0 && lane == 63) rowptr[NN] = v;  // grand total
  }
  __syncthreads();

  int base = b * 1024 + t * 4;
  int c[8][4];
#pragma unroll
  for (int xcd = 0; xcd < 8; ++xcd) {
    if (base + 3 < NN) {
      int4 v = *(const int4*)(deg8 + (size_t)xcd * NN + base);
      c[xcd][0] = v.x; c[xcd][1] = v.y; c[xcd][2] = v.z; c[xcd][3] = v.w;
    } else {
#pragma unroll
      for (int i = 0; i < 4; ++i)
        c[xcd][i] = (base + i < NN) ? deg8[(size_t)xcd * NN + base + i] : 0;
    }
  }
  int d[4];
#pragma unroll
  for (int i = 0; i < 4; ++i) {
    d[i] = 0;
#pragma unroll
    for (int xcd = 0; xcd < 8; ++xcd) d[i] += c[xcd][i];
  }
  int s = d[0] + d[1] + d[2] + d[3];
  int lane = t & 63, w = t >> 6;
  int v = s;
#pragma unroll
  for (int off = 1; off < 64; off <<= 1) {
    int u = __shfl_up(v, off);
    if (lane >= off) v += u;
  }
  if (lane == 63) wtot[w] = v;
  __syncthreads();
  int woff = 0;
#pragma unroll
  for (int i = 0; i < 4; ++i)
    if (i < w) woff += wtot[i];
  int run = offs_s + woff + (v - s);
#pragma unroll
  for (int i = 0; i < 4; ++i) {
    if (base + i < NN) {
      rowptr[base + i] = run;
      int pref = run;
#pragma unroll
      for (int xcd = 0; xcd < 8; ++xcd) {
        xoffabs[(size_t)xcd * NN + base + i] = pref;
        pref += c[xcd][i];
      }
      run += d[i];
    }
  }
}

// ---------------- main GATv2 kernel (byte-identical to r14) ----------------
// One wave per 4 consecutive targets; lane L holds channels (2L, 2L+1).
// Attrs pre-gathered into CSR order as FP16 (32B rows, induction-based
// s_loads). Per-channel W_e dot = 8x v_dot2_f32_f16 (fp16 mul, fp32 acc).

#define EDGE_PROC_H(AU, XL)                                            \
  {                                                                    \
    float e0 = 0.f, e1 = 0.f;                                          \
    _Pragma("unroll")                                                  \
    for (int jj = 0; jj < 8; ++jj) {                                   \
      half2v ha = __builtin_bit_cast(half2v, AU[jj]);                  \
      e0 = FDOT2(ha, wekA[jj], e0);                                    \
      e1 = FDOT2(ha, wekB[jj], e1);                                    \
    }                                                                  \
    es0 += e0; es1 += e1;                                              \
    float m0 = (XL.x + xr.x) + e0;                                     \
    float m1 = (XL.y + xr.y) + e1;                                     \
    float lm0 = fmaf(SLOPE, fminf(m0, 0.f), fmaxf(m0, 0.f));           \
    float lm1 = fmaf(SLOPE, fminf(m1, 0.f), fmaxf(m1, 0.f));           \
    float part = fmaf(attv.y, lm1, attv.x * lm0);                      \
    part += __shfl_xor(part, 1);                                       \
    part += __shfl_xor(part, 2);                                       \
    part += __shfl_xor(part, 4);                                       \
    part += __shfl_xor(part, 8);                                       \
    float p = __expf(part);                                            \
    lh += p;                                                           \
    acc0 = fmaf(p, XL.x, acc0);                                        \
    acc1 = fmaf(p, XL.y, acc1);                                        \
  }

__launch_bounds__(256)
__global__ void gat_kernel(const __half* __restrict__ x_l, const __half* __restrict__ x_r,
                           const int* __restrict__ rowptr, const int* __restrict__ csr_src,
                           const unsigned short* __restrict__ eattr_h,
                           const float* __restrict__ W_e,
                           const float* __restrict__ att, const float* __restrict__ bias,
                           float* __restrict__ out) {
  int wid = threadIdx.x >> 6;
  int lane = threadIdx.x & 63;
  int tbase = (blockIdx.x * 4 + wid) * 4;  // 3125*4*4 == 50000

  // wek as fp16 k-pairs: wekA[j] = (W_e[2j][2L], W_e[2j+1][2L]), wekB for 2L+1
  half2v wekA[8], wekB[8];
#pragma unroll
  for (int j = 0; j < 8; ++j) {
    float2 w0 = *(const float2*)(W_e + (2 * j) * 128 + 2 * lane);
    float2 w1 = *(const float2*)(W_e + (2 * j + 1) * 128 + 2 * lane);
    wekA[j].x = (_Float16)w0.x; wekA[j].y = (_Float16)w1.x;
    wekB[j].x = (_Float16)w0.y; wekB[j].y = (_Float16)w1.y;
  }
  float2 attv = *(const float2*)(att + 2 * lane);
  float bv = bias[(2 * lane) & 31];
  float bv1 = bias[((2 * lane) & 31) + 1];

  for (int tt = 0; tt < 4; ++tt) {
    int t = tbase + tt;
    float2 xr = __half22float2(*(const __half2*)(x_r + (size_t)t * 128 + 2 * lane));
    int start = __builtin_amdgcn_readfirstlane(rowptr[t]);
    int end = __builtin_amdgcn_readfirstlane(rowptr[t + 1]);

    float lh = 0.f, acc0 = 0.f, acc1 = 0.f, es0 = 0.f, es1 = 0.f;

    int j = start;
    for (; j + 4 <= end; j += 4) {
      int s0 = __builtin_amdgcn_readfirstlane(csr_src[j]);
      int s1 = __builtin_amdgcn_readfirstlane(csr_src[j + 1]);
      int s2 = __builtin_amdgcn_readfirstlane(csr_src[j + 2]);
      int s3 = __builtin_amdgcn_readfirstlane(csr_src[j + 3]);
      float2 xl0 = __half22float2(*(const __half2*)(x_l + (size_t)s0 * 128 + 2 * lane));
      float2 xl1 = __half22float2(*(const __half2*)(x_l + (size_t)s1 * 128 + 2 * lane));
      float2 xl2 = __half22float2(*(const __half2*)(x_l + (size_t)s2 * 128 + 2 * lane));
      float2 xl3 = __half22float2(*(const __half2*)(x_l + (size_t)s3 * 128 + 2 * lane));
      const unsigned* apg = (const unsigned*)eattr_h + (size_t)j * 8;
      unsigned A0[8], A1[8], A2[8], A3[8];
#pragma unroll
      for (int k = 0; k < 8; ++k) A0[k] = apg[k];
#pragma unroll
      for (int k = 0; k < 8; ++k) A1[k] = apg[8 + k];
#pragma unroll
      for (int k = 0; k < 8; ++k) A2[k] = apg[16 + k];
#pragma unroll
      for (int k = 0; k < 8; ++k) A3[k] = apg[24 + k];
      EDGE_PROC_H(A0, xl0)
      EDGE_PROC_H(A1, xl1)
      EDGE_PROC_H(A2, xl2)
      EDGE_PROC_H(A3, xl3)
    }
    if (j + 2 <= end) {
      int s0 = __builtin_amdgcn_readfirstlane(csr_src[j]);
      int s1 = __builtin_amdgcn_readfirstlane(csr_src[j + 1]);
      float2 xl0 = __half22float2(*(const __half2*)(x_l + (size_t)s0 * 128 + 2 * lane));
      float2 xl1 = __half22float2(*(const __half2*)(x_l + (size_t)s1 * 128 + 2 * lane));
      const unsigned* apg = (const unsigned*)eattr_h + (size_t)j * 8;
      unsigned A0[8], A1[8];
#pragma unroll
      for (int k = 0; k < 8; ++k) A0[k] = apg[k];
#pragma unroll
      for (int k = 0; k < 8; ++k) A1[k] = apg[8 + k];
      EDGE_PROC_H(A0, xl0)
      EDGE_PROC_H(A1, xl1)
      j += 2;
    }
    if (j < end) {
      int srcn = __builtin_amdgcn_readfirstlane(csr_src[j]);
      float2 xlC = __half22float2(*(const __half2*)(x_l + (size_t)srcn * 128 + 2 * lane));
      const unsigned* apg = (const unsigned*)eattr_h + (size_t)j * 8;
      unsigned A0[8];
#pragma unroll
      for (int k = 0; k < 8; ++k) A0[k] = apg[k];
      EDGE_PROC_H(A0, xlC)
    }

    // self-loop: e = es / max(deg,1); message source is x_l[t]
    {
      float rdeg = 1.0f / fmaxf((float)(end - start), 1.0f);
      float e0 = es0 * rdeg, e1 = es1 * rdeg;
      float2 xl = __half22float2(*(const __half2*)(x_l + (size_t)t * 128 + 2 * lane));
      float m0 = (xl.x + xr.x) + e0;
      float m1 = (xl.y + xr.y) + e1;
      float lm0 = fmaf(SLOPE, fminf(m0, 0.f), fmaxf(m0, 0.f));
      float lm1 = fmaf(SLOPE, fminf(m1, 0.f), fmaxf(m1, 0.f));
      float part = fmaf(attv.y, lm1, attv.x * lm0);
      part += __shfl_xor(part, 1);
      part += __shfl_xor(part, 2);
      part += __shfl_xor(part, 4);
      part += __shfl_xor(part, 8);
      float p = __expf(part);
      lh += p;
      acc0 = fmaf(p, xl.x, acc0);
      acc1 = fmaf(p, xl.y, acc1);
    }

    float inv = 1.0f / lh;
    float v0 = acc0 * inv, v1 = acc1 * inv;
    v0 += __shfl_xor(v0, 16);
    v0 += __shfl_xor(v0, 32);
    v1 += __shfl_xor(v1, 16);
    v1 += __shfl_xor(v1, 32);
    if (lane < 16) {
      float o0 = fmaf(v0, 0.25f, bv);
      float o1 = fmaf(v1, 0.25f, bv1);
      o0 = fmaf(SLOPE, fminf(o0, 0.f), fmaxf(o0, 0.f));
      o1 = fmaf(SLOPE, fminf(o1, 0.f), fmaxf(o1, 0.f));
      *(float2*)(out + (size_t)t * 32 + 2 * lane) = make_float2(o0, o1);
    }
  }
}

// ---------------- launch ----------------

extern "C" void kernel_launch(void* const* d_in, const int* in_sizes, int n_in,
                              void* d_out, int out_size, void* d_ws, size_t ws_size,
                              hipStream_t stream) {
  const float* x = (const float*)d_in[0];
  const int* ei = (const int*)d_in[1];
  const float* eattr = (const float*)d_in[2];
  const float* W_l = (const float*)d_in[3];
  const float* b_l = (const float*)d_in[4];
  const float* W_r = (const float*)d_in[5];
  const float* b_r = (const float*)d_in[6];
  const float* W_e = (const float*)d_in[7];
  const float* att = (const float*)d_in[8];
  const float* bias = (const float*)d_in[9];
  float* out = (float*)d_out;

  char* ws = (char*)d_ws;
  int* csr_src = (int*)ws;                                    // 3,200,000 B
  unsigned short* eattr_h = (unsigned short*)(ws + 3200000);  // 25,600,000 B
  __half* x_l = (__half*)(ws + 28800000);                     // 12,800,000 B
  __half* x_r = (__half*)(ws + 41600000);                     // 12,800,000 B
  int* deg8 = (int*)(ws + 54400000);                          // 1,600,000 B
  int* rowptr = (int*)(ws + 56000000);                        // 200,004 B
  int* rank = (int*)(ws + 56200016);                          // 3,200,000 B
  int* xoffabs = (int*)(ws + 59400016);                       // 1,600,000 B
  int* psum = (int*)(ws + 61000016);                          // 196 B

  hipMemsetAsync(deg8, 0, 8 * NN * sizeof(int), stream);
  fusedA_kernel<<<GEMMB + EDGEB, 256, 0, stream>>>(x, W_l, b_l, x_l, ei + NE, deg8, rank);
  partial_kernel<<<NB, 256, 0, stream>>>(deg8, psum);
  final_kernel<<<NB, 256, 0, stream>>>(deg8, psum, rowptr, xoffabs);
  fusedB_kernel<<<GEMMB + EDGEB, 256, 0, stream>>>(
      x, W_r, b_r, x_r, ei, ei + NE, rank, xoffabs, (const float4*)eattr,
      csr_src, eattr_h);
  gat_kernel<<<NN / 16, 256, 0, stream>>>(x_l, x_r, rowptr, csr_src, eattr_h, W_e, att, bias, out);
}